// Round 6
// baseline (1925.564 us; speedup 1.0000x reference)
//
#include <hip/hip_runtime.h>
#include <hip/hip_bf16.h>

#define S_LEN 1024
#define E_DIM 512
#define INNER_D 1024
#define NHEAD 8
#define DHEAD 128

// ---------------- embedding: x = concat(x_enc, x_mark_enc) @ emb_W + emb_b ----------------
__global__ __launch_bounds__(128) void embed_kernel(
    const float* __restrict__ xe, const float* __restrict__ xm,
    const float* __restrict__ W, const float* __restrict__ bias,
    float* __restrict__ x)
{
  int row = blockIdx.x;  // b*S+s, 2048 rows
  int tid = threadIdx.x;
  __shared__ float in_s[25];
  if (tid < 21) in_s[tid] = xe[row * 21 + tid];
  else if (tid < 25) in_s[tid] = xm[row * 4 + tid - 21];
  __syncthreads();
#pragma unroll
  for (int rep = 0; rep < 4; rep++) {
    int e = tid + rep * 128;
    float acc = bias[e];
#pragma unroll
    for (int i = 0; i < 25; i++) acc += in_s[i] * W[i * E_DIM + e];
    x[(size_t)row * E_DIM + e] = acc;
  }
}

// ---------------- layernorm (weight only, eps=1e-5), E=512, block=256 ----------------
__global__ __launch_bounds__(256) void ln_kernel(
    const float* __restrict__ x, const float* __restrict__ w, float* __restrict__ out)
{
  int row = blockIdx.x, tid = threadIdx.x;
  const float* xr = x + (size_t)row * E_DIM;
  float2 v = *(const float2*)(xr + tid * 2);
  float s = v.x + v.y, q = v.x * v.x + v.y * v.y;
#pragma unroll
  for (int off = 32; off; off >>= 1) { s += __shfl_xor(s, off); q += __shfl_xor(q, off); }
  __shared__ float ssum[4], ssq[4];
  int wv = tid >> 6;
  if ((tid & 63) == 0) { ssum[wv] = s; ssq[wv] = q; }
  __syncthreads();
  s = ssum[0] + ssum[1] + ssum[2] + ssum[3];
  q = ssq[0] + ssq[1] + ssq[2] + ssq[3];
  float mu = s * (1.f / E_DIM);
  float var = q * (1.f / E_DIM) - mu * mu;
  float rs = rsqrtf(var + 1e-5f);
  int e = tid * 2;
  float2 o;
  o.x = (v.x - mu) * rs * w[e];
  o.y = (v.y - mu) * rs * w[e + 1];
  *(float2*)(out + (size_t)row * E_DIM + e) = o;
}

__global__ __launch_bounds__(256) void ln_final_kernel(
    const float* __restrict__ x, const float* __restrict__ w, float* __restrict__ out)
{
  int ridx = blockIdx.x;  // 0..191
  int b = ridx / 96, r = ridx % 96;
  int row = b * S_LEN + (S_LEN - 96) + r;
  int tid = threadIdx.x;
  const float* xr = x + (size_t)row * E_DIM;
  float2 v = *(const float2*)(xr + tid * 2);
  float s = v.x + v.y, q = v.x * v.x + v.y * v.y;
#pragma unroll
  for (int off = 32; off; off >>= 1) { s += __shfl_xor(s, off); q += __shfl_xor(q, off); }
  __shared__ float ssum[4], ssq[4];
  int wv = tid >> 6;
  if ((tid & 63) == 0) { ssum[wv] = s; ssq[wv] = q; }
  __syncthreads();
  s = ssum[0] + ssum[1] + ssum[2] + ssum[3];
  q = ssq[0] + ssq[1] + ssq[2] + ssq[3];
  float mu = s * (1.f / E_DIM);
  float var = q * (1.f / E_DIM) - mu * mu;
  float rs = rsqrtf(var + 1e-5f);
  int e = tid * 2;
  float2 o;
  o.x = (v.x - mu) * rs * w[e];
  o.y = (v.y - mu) * rs * w[e + 1];
  *(float2*)(out + (size_t)ridx * E_DIM + e) = o;
}

// ---------------- tiled GEMM: C[M,N] (+)= A[M,K] @ B[K,N], f32; optional column-split C ----------------
template <int ADD>
__global__ __launch_bounds__(256) void gemm_f32(
    const float* __restrict__ A, const float* __restrict__ Bw,
    float* __restrict__ C0, float* __restrict__ C1,
    int M, int N, int K, int lda, int split_col, int ldc)
{
  __shared__ float As[16][68];
  __shared__ float Bs[16][68];
  const int tid = threadIdx.x;
  const int tx = tid & 15, ty = tid >> 4;
  const int row0 = blockIdx.y * 64, col0 = blockIdx.x * 64;
  const int mA = tid >> 2;         // 0..63
  const int kA = (tid & 3) * 4;    // 0,4,8,12
  const int kB = tid >> 6;         // 0..3
  const int nB = tid & 63;
  float acc[4][4] = {};
  for (int k0 = 0; k0 < K; k0 += 16) {
    float4 a4 = *(const float4*)(A + (size_t)(row0 + mA) * lda + k0 + kA);
    As[kA + 0][mA] = a4.x; As[kA + 1][mA] = a4.y; As[kA + 2][mA] = a4.z; As[kA + 3][mA] = a4.w;
#pragma unroll
    for (int i = 0; i < 4; i++) {
      int kk = kB + i * 4;
      Bs[kk][nB] = Bw[(size_t)(k0 + kk) * N + col0 + nB];
    }
    __syncthreads();
#pragma unroll
    for (int k = 0; k < 16; k++) {
      float4 a = *(const float4*)&As[k][ty * 4];
      float4 b = *(const float4*)&Bs[k][tx * 4];
      acc[0][0] += a.x * b.x; acc[0][1] += a.x * b.y; acc[0][2] += a.x * b.z; acc[0][3] += a.x * b.w;
      acc[1][0] += a.y * b.x; acc[1][1] += a.y * b.y; acc[1][2] += a.y * b.z; acc[1][3] += a.y * b.w;
      acc[2][0] += a.z * b.x; acc[2][1] += a.z * b.y; acc[2][2] += a.z * b.z; acc[2][3] += a.z * b.w;
      acc[3][0] += a.w * b.x; acc[3][1] += a.w * b.y; acc[3][2] += a.w * b.z; acc[3][3] += a.w * b.w;
    }
    __syncthreads();
  }
  float* Cb = C0;
  int ccol = col0;
  if (C1 && col0 >= split_col) { Cb = C1; ccol = col0 - split_col; }
#pragma unroll
  for (int i = 0; i < 4; i++) {
    float* cp = Cb + (size_t)(row0 + ty * 4 + i) * ldc + ccol + tx * 4;
    if (ADD) {
      cp[0] += acc[i][0]; cp[1] += acc[i][1]; cp[2] += acc[i][2]; cp[3] += acc[i][3];
    } else {
      float4 st; st.x = acc[i][0]; st.y = acc[i][1]; st.z = acc[i][2]; st.w = acc[i][3];
      *(float4*)cp = st;
    }
  }
}

// ---------------- causal depthwise conv (K=4) + bias + SiLU ----------------
__global__ __launch_bounds__(256) void conv_silu_kernel(
    const float* __restrict__ xm, const float* __restrict__ cw, const float* __restrict__ cb,
    float* __restrict__ xc)
{
  int idx = blockIdx.x * 256 + threadIdx.x;  // B*S*256
  int g = idx & 255;
  int row = idx >> 8;
  int s = row & (S_LEN - 1);
  int c0 = g * 4;
  const float* base = xm + (size_t)row * INNER_D + c0;
  float4 acc = {0.f, 0.f, 0.f, 0.f};
#pragma unroll
  for (int kk = 0; kk < 4; kk++) {
    int ts = s - 3 + kk;
    if (ts >= 0) {
      float4 xv = *(const float4*)(base + (ptrdiff_t)(kk - 3) * INNER_D);
      acc.x += xv.x * cw[(c0 + 0) * 4 + kk];
      acc.y += xv.y * cw[(c0 + 1) * 4 + kk];
      acc.z += xv.z * cw[(c0 + 2) * 4 + kk];
      acc.w += xv.w * cw[(c0 + 3) * 4 + kk];
    }
  }
  acc.x += cb[c0 + 0]; acc.y += cb[c0 + 1];
  acc.z += cb[c0 + 2]; acc.w += cb[c0 + 3];
  acc.x = acc.x / (1.f + __expf(-acc.x));
  acc.y = acc.y / (1.f + __expf(-acc.y));
  acc.z = acc.z / (1.f + __expf(-acc.z));
  acc.w = acc.w / (1.f + __expf(-acc.w));
  *(float4*)(xc + (size_t)row * INNER_D + c0) = acc;
}

// ---------------- headwise 4x4 projections: q,k from xc; v from xm ----------------
__global__ __launch_bounds__(256) void qkv_headwise_kernel(
    const float* __restrict__ xc, const float* __restrict__ xm,
    const float* __restrict__ qw, const float* __restrict__ kw, const float* __restrict__ vw,
    float* __restrict__ q, float* __restrict__ k, float* __restrict__ v)
{
  int idx = blockIdx.x * 256 + threadIdx.x;
  int g = idx & 255;
  size_t row = idx >> 8;
  float4 xc4 = *(const float4*)(xc + row * INNER_D + g * 4);
  float4 xm4 = *(const float4*)(xm + row * INNER_D + g * 4);
  const float* qg = qw + g * 16;
  const float* kg = kw + g * 16;
  const float* vg = vw + g * 16;
  float xcv[4] = {xc4.x, xc4.y, xc4.z, xc4.w};
  float xmv[4] = {xm4.x, xm4.y, xm4.z, xm4.w};
  float qo[4], ko[4], vo[4];
#pragma unroll
  for (int o = 0; o < 4; o++) {
    float aq = 0.f, ak = 0.f, av = 0.f;
#pragma unroll
    for (int d = 0; d < 4; d++) {
      aq += xcv[d] * qg[o * 4 + d];
      ak += xcv[d] * kg[o * 4 + d];
      av += xmv[d] * vg[o * 4 + d];
    }
    qo[o] = aq; ko[o] = ak; vo[o] = av;
  }
  float4 qs = {qo[0], qo[1], qo[2], qo[3]};
  float4 ks = {ko[0], ko[1], ko[2], ko[3]};
  float4 vs = {vo[0], vo[1], vo[2], vo[3]};
  *(float4*)(q + row * INNER_D + g * 4) = qs;
  *(float4*)(k + row * INNER_D + g * 4) = ks;
  *(float4*)(v + row * INNER_D + g * 4) = vs;
}

// ---------------- gate GEMVs: ig/fg[b,n,s] ----------------
__global__ __launch_bounds__(256) void gates_kernel(
    const float* __restrict__ q, const float* __restrict__ k, const float* __restrict__ v,
    const float* __restrict__ igW, const float* __restrict__ igb,
    const float* __restrict__ fgW, const float* __restrict__ fgb,
    float* __restrict__ ig, float* __restrict__ fg)
{
  int row = blockIdx.x;
  int b = row >> 10, s = row & (S_LEN - 1);
  int tid = threadIdx.x;
  float ia[8] = {}, fa[8] = {};
#pragma unroll
  for (int i = 0; i < 12; i++) {
    int j = tid + i * 256;
    float xv;
    if (j < 1024) xv = q[(size_t)row * INNER_D + j];
    else if (j < 2048) xv = k[(size_t)row * INNER_D + j - 1024];
    else xv = v[(size_t)row * INNER_D + j - 2048];
    float4 wi0 = *(const float4*)(igW + (size_t)j * 8);
    float4 wi1 = *(const float4*)(igW + (size_t)j * 8 + 4);
    float4 wf0 = *(const float4*)(fgW + (size_t)j * 8);
    float4 wf1 = *(const float4*)(fgW + (size_t)j * 8 + 4);
    ia[0] += xv * wi0.x; ia[1] += xv * wi0.y; ia[2] += xv * wi0.z; ia[3] += xv * wi0.w;
    ia[4] += xv * wi1.x; ia[5] += xv * wi1.y; ia[6] += xv * wi1.z; ia[7] += xv * wi1.w;
    fa[0] += xv * wf0.x; fa[1] += xv * wf0.y; fa[2] += xv * wf0.z; fa[3] += xv * wf0.w;
    fa[4] += xv * wf1.x; fa[5] += xv * wf1.y; fa[6] += xv * wf1.z; fa[7] += xv * wf1.w;
  }
#pragma unroll
  for (int off = 32; off; off >>= 1) {
#pragma unroll
    for (int n = 0; n < 8; n++) {
      ia[n] += __shfl_xor(ia[n], off);
      fa[n] += __shfl_xor(fa[n], off);
    }
  }
  __shared__ float red[2][4][8];
  int wv = tid >> 6;
  if ((tid & 63) == 0) {
#pragma unroll
    for (int n = 0; n < 8; n++) { red[0][wv][n] = ia[n]; red[1][wv][n] = fa[n]; }
  }
  __syncthreads();
  if (tid < 8) {
    float si = red[0][0][tid] + red[0][1][tid] + red[0][2][tid] + red[0][3][tid];
    float sf = red[1][0][tid] + red[1][1][tid] + red[1][2][tid] + red[1][3][tid];
    size_t o = ((size_t)(b * NHEAD + tid) << 10) + s;
    ig[o] = si + igb[tid];
    fg[o] = sf + fgb[tid];
  }
}

// ---------------- per-(b,h) scans ----------------
__global__ __launch_bounds__(1024) void scan_kernel(
    const float* __restrict__ ig, const float* __restrict__ fg,
    float* __restrict__ a, float* __restrict__ rm, float* __restrict__ enm)
{
  int bh = blockIdx.x;
  int t = threadIdx.x;
  __shared__ float buf[1024];
  size_t o = ((size_t)bh << 10) + t;
  float f = fg[o];
  float lf = (f >= 0.f) ? -log1pf(__expf(-f)) : f - log1pf(__expf(f));
  buf[t] = lf;
  __syncthreads();
  float run = lf;
  for (int off = 1; off < 1024; off <<= 1) {
    float add = (t >= off) ? buf[t - off] : 0.f;
    __syncthreads();
    run += add;
    buf[t] = run;
    __syncthreads();
  }
  float cs = run;
  float av = ig[o] - cs;
  a[o] = av;
  buf[t] = av;
  __syncthreads();
  float rmx = av;
  for (int off = 1; off < 1024; off <<= 1) {
    float m = (t >= off) ? buf[t - off] : -3.4e38f;
    __syncthreads();
    rmx = fmaxf(rmx, m);
    buf[t] = rmx;
    __syncthreads();
  }
  rm[o] = rmx;
  enm[o] = __expf(-(cs + rmx));
}

// ---------------- split-K chunked attention ----------------
// 40 chunks per bh, descending size (LPT): entry = (qt, kc0), nk = min(4, qt+1-kc0).
__device__ __constant__ int c_qt[40] = {
  3,4,5,6,7,7,8,8,9,9,10,10,11,11,11,12,12,12,13,13,13,14,14,14,15,15,15,15,
  2,6,10,14, 1,5,9,13, 0,4,8,12};
__device__ __constant__ int c_kc[40] = {
  0,0,0,0,0,4,0,4,0,4,0,4,0,4,8,0,4,8,0,4,8,0,4,8,0,4,8,12,
  0,4,8,12, 0,4,8,12, 0,4,8,12};

// block = 256 threads, one (bh, qt, kc0..kc0+nk-1) chunk; partials -> hsum/scsum via atomicAdd.
__global__ __launch_bounds__(256) void attn_chunk_kernel(
    const float* __restrict__ q, const float* __restrict__ k, const float* __restrict__ v,
    const float* __restrict__ a_arr, const float* __restrict__ rm_arr,
    float* __restrict__ hsum, float* __restrict__ scsum)
{
  const int bh = blockIdx.x;      // 0..15
  const int ci = blockIdx.y;      // 0..39
  const int qt = c_qt[ci];
  const int kc0 = c_kc[ci];
  const int nk = min(4, qt + 1 - kc0);
  const int b = bh >> 3, h = bh & 7;
  const int s0 = qt * 64;
  const int tid = threadIdx.x;
  const int tx = tid & 15, ty = tid >> 4;
  const size_t rowbase = (size_t)b * S_LEN;
  const int c0 = h * DHEAD;

  __shared__ float Qs[64 * 132];
  __shared__ float KsW[64 * 132];  // K tile [col][d]; reused as w[64][68] after phase A
  __shared__ float Vs[64 * 132];
  __shared__ float as_[64];

  // stage Q tile
#pragma unroll
  for (int rep = 0; rep < 8; rep++) {
    int idx = rep * 256 + tid;
    int r = idx >> 5, f4 = idx & 31;
    *(float4*)&Qs[r * 132 + f4 * 4] =
        *(const float4*)(q + (rowbase + s0 + r) * INNER_D + c0 + f4 * 4);
  }
  float rmv[4];
#pragma unroll
  for (int i = 0; i < 4; i++) rmv[i] = rm_arr[(size_t)bh * S_LEN + s0 + ty * 4 + i];

  float accH[4][8] = {};
  float sc_part[4] = {0.f, 0.f, 0.f, 0.f};
  const float scale = 0.08838834764831845f;  // 1/sqrt(128)

  for (int kki = 0; kki < nk; kki++) {
    const int t0 = (kc0 + kki) * 64;
    __syncthreads();
#pragma unroll
    for (int rep = 0; rep < 8; rep++) {
      int idx = rep * 256 + tid;
      int r = idx >> 5, f4 = idx & 31;
      *(float4*)&KsW[r * 132 + f4 * 4] =
          *(const float4*)(k + (rowbase + t0 + r) * INNER_D + c0 + f4 * 4);
      *(float4*)&Vs[r * 132 + f4 * 4] =
          *(const float4*)(v + (rowbase + t0 + r) * INNER_D + c0 + f4 * 4);
    }
    if (tid < 64) as_[tid] = a_arr[(size_t)bh * S_LEN + t0 + tid];
    __syncthreads();

    // phase A: p[i][j] = Q[s0+ty*4+i] . K[t0 + j*16+tx]  (K reads 2-way = free)
    float p[4][4] = {};
    for (int d4 = 0; d4 < 32; d4++) {
      int d = d4 * 4;
      float4 qv[4], kv[4];
#pragma unroll
      for (int i = 0; i < 4; i++) qv[i] = *(const float4*)&Qs[(ty * 4 + i) * 132 + d];
#pragma unroll
      for (int j = 0; j < 4; j++) kv[j] = *(const float4*)&KsW[(j * 16 + tx) * 132 + d];
#pragma unroll
      for (int i = 0; i < 4; i++)
#pragma unroll
        for (int j = 0; j < 4; j++)
          p[i][j] += qv[i].x * kv[j].x + qv[i].y * kv[j].y + qv[i].z * kv[j].z + qv[i].w * kv[j].w;
    }
    __syncthreads();  // K reads done before w overwrites KsW

    // w + causal mask + row-sum partials; w[row][col] stride 68
#pragma unroll
    for (int i = 0; i < 4; i++) {
      int sg = s0 + ty * 4 + i;
#pragma unroll
      for (int j = 0; j < 4; j++) {
        int cl = j * 16 + tx;
        float w = p[i][j] * scale * __expf(as_[cl] - rmv[i]);
        if (t0 + cl > sg) w = 0.f;
        sc_part[i] += w;
        KsW[(ty * 4 + i) * 68 + cl] = w;
      }
    }
    __syncthreads();

    // phase B: accH[i][0..3] = H cols tx*4..+3 ; accH[i][4..7] = cols 64+tx*4..+3 (2-way reads)
    for (int c4 = 0; c4 < 16; c4++) {
      int c = c4 * 4;
      float wq[4][4];
#pragma unroll
      for (int i = 0; i < 4; i++) {
        float4 wr = *(const float4*)&KsW[(ty * 4 + i) * 68 + c];
        wq[i][0] = wr.x; wq[i][1] = wr.y; wq[i][2] = wr.z; wq[i][3] = wr.w;
      }
#pragma unroll
      for (int cj = 0; cj < 4; cj++) {
        float4 va = *(const float4*)&Vs[(c + cj) * 132 + tx * 4];
        float4 vb = *(const float4*)&Vs[(c + cj) * 132 + 64 + tx * 4];
#pragma unroll
        for (int i = 0; i < 4; i++) {
          float wf = wq[i][cj];
          accH[i][0] += wf * va.x; accH[i][1] += wf * va.y;
          accH[i][2] += wf * va.z; accH[i][3] += wf * va.w;
          accH[i][4] += wf * vb.x; accH[i][5] += wf * vb.y;
          accH[i][6] += wf * vb.z; accH[i][7] += wf * vb.w;
        }
      }
    }
  }

  // accumulate partials
#pragma unroll
  for (int i = 0; i < 4; i++) {
    int row = (bh << 10) + s0 + ty * 4 + i;
    atomicAdd(&scsum[row], sc_part[i]);
    float* hb = hsum + (size_t)row * 128;
#pragma unroll
    for (int c = 0; c < 4; c++) atomicAdd(&hb[tx * 4 + c], accH[i][c]);
#pragma unroll
    for (int c = 0; c < 4; c++) atomicAdd(&hb[64 + tx * 4 + c], accH[i][4 + c]);
  }
}

// epilogue: norm -> headwise LN -> *onw + skip*xc -> *silu(z) -> hs. One wave per row.
__global__ __launch_bounds__(256) void attn_epilogue_kernel(
    const float* __restrict__ hsum, const float* __restrict__ scsum,
    const float* __restrict__ enm,
    const float* __restrict__ xc, const float* __restrict__ z,
    const float* __restrict__ skip, const float* __restrict__ onw,
    float* __restrict__ hs)
{
  int wave = threadIdx.x >> 6, lane = threadIdx.x & 63;
  int gr = blockIdx.x * 4 + wave;   // (bh<<10)+s, 0..16383
  int bh = gr >> 10, s = gr & 1023;
  int b = bh >> 3, hh = bh & 7;
  float2 h2 = *(const float2*)(hsum + (size_t)gr * 128 + lane * 2);
  float nrm = fmaxf(fabsf(scsum[gr]), enm[gr]);
  float inv = 1.f / (nrm + 1e-6f);
  float hx = h2.x * inv, hy = h2.y * inv;
  float sm = hx + hy, sq = hx * hx + hy * hy;
#pragma unroll
  for (int off = 32; off; off >>= 1) { sm += __shfl_xor(sm, off); sq += __shfl_xor(sq, off); }
  float mu = sm * (1.f / DHEAD);
  float var = sq * (1.f / DHEAD) - mu * mu;
  float rs = rsqrtf(var + 1e-5f);
  int c0 = hh * DHEAD + lane * 2;
  size_t base = ((size_t)(b * S_LEN + s)) * INNER_D + c0;
  float2 xc2 = *(const float2*)(xc + base);
  float2 z2  = *(const float2*)(z + base);
  float skx = skip[c0], sky = skip[c0 + 1];
  float owx = onw[c0],  owy = onw[c0 + 1];
  float2 o;
  o.x = ((hx - mu) * rs * owx + skx * xc2.x) * (z2.x / (1.f + __expf(-z2.x)));
  o.y = ((hy - mu) * rs * owy + sky * xc2.y) * (z2.y / (1.f + __expf(-z2.y)));
  *(float2*)(hs + base) = o;
}

// ---------------- head: out[192,21] = ln96 @ head_W + head_b, store f32 ----------------
__global__ __launch_bounds__(64) void head_kernel(
    const float* __restrict__ ln96, const float* __restrict__ hW, const float* __restrict__ hb,
    float* __restrict__ out)
{
  int row = blockIdx.x;  // 0..191
  int n = threadIdx.x;
  if (n >= 21) return;
  float acc = hb[n];
  const float* xr = ln96 + (size_t)row * E_DIM;
  for (int kk = 0; kk < E_DIM; kk++) acc += xr[kk] * hW[kk * 21 + n];
  out[row * 21 + n] = acc;
}

extern "C" void kernel_launch(void* const* d_in, const int* in_sizes, int n_in,
                              void* d_out, int out_size, void* d_ws, size_t ws_size,
                              hipStream_t stream)
{
  const float* x_enc   = (const float*)d_in[0];
  const float* x_mark  = (const float*)d_in[1];
  const float* emb_W   = (const float*)d_in[4];
  const float* emb_b   = (const float*)d_in[5];
  const float* ln_w    = (const float*)d_in[6];
  const float* up_W    = (const float*)d_in[7];
  const float* conv_W  = (const float*)d_in[8];
  const float* conv_b  = (const float*)d_in[9];
  const float* q_W     = (const float*)d_in[10];
  const float* k_W     = (const float*)d_in[11];
  const float* v_W     = (const float*)d_in[12];
  const float* ig_W    = (const float*)d_in[13];
  const float* ig_b    = (const float*)d_in[14];
  const float* fg_W    = (const float*)d_in[15];
  const float* fg_b    = (const float*)d_in[16];
  const float* skip_w  = (const float*)d_in[17];
  const float* onorm_w = (const float*)d_in[18];
  const float* down_W  = (const float*)d_in[19];
  const float* post_ln = (const float*)d_in[20];
  const float* head_W  = (const float*)d_in[21];
  const float* head_b  = (const float*)d_in[22];

  float* p = (float*)d_ws;
  float* x    = p; p += 1048576;   // 2048*512
  float* xn   = p; p += 1048576;   // LN out; dead after up-GEMM -> reused as hsum lower half
  float* hext = p; p += 1048576;   // hsum upper half (contiguous with xn)
  float* xm   = p; p += 2097152;   // 2048*1024 (reused as hs after qkv)
  float* z    = p; p += 2097152;
  float* xc   = p; p += 2097152;
  float* qb   = p; p += 2097152;
  float* kb   = p; p += 2097152;
  float* vb   = p; p += 2097152;
  float* igb_ = p; p += 16384;     // 16*1024
  float* fgb_ = p; p += 16384;
  float* ab   = p; p += 16384;
  float* rmb  = p; p += 16384;
  float* enmb = p; p += 16384;
  float* scsum= p; p += 16384;
  float* ln96 = p; p += 98304;     // 192*512
  float* hsb  = xm;                // alias: xm dead after qkv_headwise
  float* hsum = xn;                // spans xn+hext = 2097152 floats (16*1024*128)
  (void)hext;

  embed_kernel<<<2048, 128, 0, stream>>>(x_enc, x_mark, emb_W, emb_b, x);

  for (int L = 0; L < 4; L++) {
    ln_kernel<<<2048, 256, 0, stream>>>(x, ln_w + L * 512, xn);
    gemm_f32<0><<<dim3(32, 32), 256, 0, stream>>>(
        xn, up_W + (size_t)L * 512 * 2048, xm, z, 2048, 2048, 512, 512, 1024, 1024);
    conv_silu_kernel<<<2048, 256, 0, stream>>>(xm, conv_W + L * 4096, conv_b + L * 1024, xc);
    qkv_headwise_kernel<<<2048, 256, 0, stream>>>(
        xc, xm, q_W + L * 4096, k_W + L * 4096, v_W + L * 4096, qb, kb, vb);
    gates_kernel<<<2048, 256, 0, stream>>>(
        qb, kb, vb, ig_W + L * 24576, ig_b + L * 8, fg_W + L * 24576, fg_b + L * 8, igb_, fgb_);
    scan_kernel<<<16, 1024, 0, stream>>>(igb_, fgb_, ab, rmb, enmb);
    hipMemsetAsync(hsum, 0, 2097152 * sizeof(float), stream);
    hipMemsetAsync(scsum, 0, 16384 * sizeof(float), stream);
    attn_chunk_kernel<<<dim3(16, 40), 256, 0, stream>>>(qb, kb, vb, ab, rmb, hsum, scsum);
    attn_epilogue_kernel<<<4096, 256, 0, stream>>>(
        hsum, scsum, enmb, xc, z, skip_w + L * 1024, onorm_w + L * 1024, hsb);
    gemm_f32<1><<<dim3(8, 32), 256, 0, stream>>>(
        hsb, down_W + (size_t)L * 1024 * 512, x, nullptr, 2048, 512, 1024, 1024, 1 << 30, 512);
  }

  ln_final_kernel<<<192, 256, 0, stream>>>(x, post_ln, ln96);
  head_kernel<<<192, 64, 0, stream>>>(ln96, head_W, head_b, (float*)d_out);
}

// Round 7
// 1320.469 us; speedup vs baseline: 1.4582x; 1.4582x over previous
//
#include <hip/hip_runtime.h>
#include <hip/hip_bf16.h>

#define S_LEN 1024
#define E_DIM 512
#define INNER_D 1024
#define NHEAD 8
#define DHEAD 128

typedef unsigned short u16;
typedef unsigned int u32;
typedef __attribute__((ext_vector_type(8))) short short8;
typedef __attribute__((ext_vector_type(4))) float f32x4;

__device__ __forceinline__ u16 f2bf(float f) {
  u32 u = __float_as_uint(f);
  u32 r = u + 0x7FFFu + ((u >> 16) & 1u);
  return (u16)(r >> 16);
}

// ---------------- embedding ----------------
__global__ __launch_bounds__(128) void embed_kernel(
    const float* __restrict__ xe, const float* __restrict__ xm,
    const float* __restrict__ W, const float* __restrict__ bias,
    float* __restrict__ x)
{
  int row = blockIdx.x;
  int tid = threadIdx.x;
  __shared__ float in_s[25];
  if (tid < 21) in_s[tid] = xe[row * 21 + tid];
  else if (tid < 25) in_s[tid] = xm[row * 4 + tid - 21];
  __syncthreads();
#pragma unroll
  for (int rep = 0; rep < 4; rep++) {
    int e = tid + rep * 128;
    float acc = bias[e];
#pragma unroll
    for (int i = 0; i < 25; i++) acc += in_s[i] * W[i * E_DIM + e];
    x[(size_t)row * E_DIM + e] = acc;
  }
}

// ---------------- layernorm -> bf16 output (A operand for up-GEMM) ----------------
__global__ __launch_bounds__(256) void ln_kernel(
    const float* __restrict__ x, const float* __restrict__ w, u16* __restrict__ out)
{
  int row = blockIdx.x, tid = threadIdx.x;
  const float* xr = x + (size_t)row * E_DIM;
  float2 v = *(const float2*)(xr + tid * 2);
  float s = v.x + v.y, q = v.x * v.x + v.y * v.y;
#pragma unroll
  for (int off = 32; off; off >>= 1) { s += __shfl_xor(s, off); q += __shfl_xor(q, off); }
  __shared__ float ssum[4], ssq[4];
  int wv = tid >> 6;
  if ((tid & 63) == 0) { ssum[wv] = s; ssq[wv] = q; }
  __syncthreads();
  s = ssum[0] + ssum[1] + ssum[2] + ssum[3];
  q = ssq[0] + ssq[1] + ssq[2] + ssq[3];
  float mu = s * (1.f / E_DIM);
  float var = q * (1.f / E_DIM) - mu * mu;
  float rs = rsqrtf(var + 1e-5f);
  int e = tid * 2;
  ushort2 o;
  o.x = f2bf((v.x - mu) * rs * w[e]);
  o.y = f2bf((v.y - mu) * rs * w[e + 1]);
  *(ushort2*)(out + (size_t)row * E_DIM + e) = o;
}

__global__ __launch_bounds__(256) void ln_final_kernel(
    const float* __restrict__ x, const float* __restrict__ w, float* __restrict__ out)
{
  int ridx = blockIdx.x;
  int b = ridx / 96, r = ridx % 96;
  int row = b * S_LEN + (S_LEN - 96) + r;
  int tid = threadIdx.x;
  const float* xr = x + (size_t)row * E_DIM;
  float2 v = *(const float2*)(xr + tid * 2);
  float s = v.x + v.y, q = v.x * v.x + v.y * v.y;
#pragma unroll
  for (int off = 32; off; off >>= 1) { s += __shfl_xor(s, off); q += __shfl_xor(q, off); }
  __shared__ float ssum[4], ssq[4];
  int wv = tid >> 6;
  if ((tid & 63) == 0) { ssum[wv] = s; ssq[wv] = q; }
  __syncthreads();
  s = ssum[0] + ssum[1] + ssum[2] + ssum[3];
  q = ssq[0] + ssq[1] + ssq[2] + ssq[3];
  float mu = s * (1.f / E_DIM);
  float var = q * (1.f / E_DIM) - mu * mu;
  float rs = rsqrtf(var + 1e-5f);
  int e = tid * 2;
  float2 o;
  o.x = (v.x - mu) * rs * w[e];
  o.y = (v.y - mu) * rs * w[e + 1];
  *(float2*)(out + (size_t)ridx * E_DIM + e) = o;
}

// ---------------- transpose f32 [K][N] -> bf16 [N][K] (weights, once per layer) ----------------
__global__ __launch_bounds__(256) void transpose_bf16_kernel(
    const float* __restrict__ in, u16* __restrict__ out, int K, int N)
{
  __shared__ u16 T[64][72];
  int k0 = blockIdx.x * 64, n0 = blockIdx.y * 64;
  int t = threadIdx.x;
  int kr = t >> 2, nseg = (t & 3) * 16;
  const float* src = in + (size_t)(k0 + kr) * N + n0 + nseg;
#pragma unroll
  for (int j = 0; j < 16; j++) T[kr][nseg + j] = f2bf(src[j]);
  __syncthreads();
  int nr = t >> 2, kseg = (t & 3) * 16;
  u32 u[8];
#pragma unroll
  for (int rr = 0; rr < 8; rr++) {
    u32 lo = T[kseg + 2 * rr][nr];
    u32 hi = T[kseg + 2 * rr + 1][nr];
    u[rr] = lo | (hi << 16);
  }
  u16* dst = out + (size_t)(n0 + nr) * K + k0 + kseg;
  uint4 w0 = {u[0], u[1], u[2], u[3]};
  uint4 w1 = {u[4], u[5], u[6], u[7]};
  *(uint4*)dst = w0;
  *(uint4*)(dst + 8) = w1;
}

// ---------------- bf16 MFMA GEMM: C[M,N] (+)= A[M,K] @ Bt[N,K]^T ----------------
// A [M][K] bf16 row-major; Bt [N][K] bf16 row-major. BM=BN=128, BK=32.
// grid=(N/128, M/128), block=256 (4 waves; wave = 64x64 via 4x4 mfma 16x16x32).
template <int ADD>
__global__ __launch_bounds__(256) void gemm_bf16(
    const u16* __restrict__ A, const u16* __restrict__ Bt,
    float* __restrict__ C0, float* __restrict__ C1,
    int M, int N, int K, int split_col, int ldc)
{
  __shared__ u16 As[128][40];
  __shared__ u16 Bs[128][40];
  const int tid = threadIdx.x;
  const int row0 = blockIdx.y * 128, col0 = blockIdx.x * 128;
  const int wave = tid >> 6, lane = tid & 63;
  const int wr = wave >> 1, wc = wave & 1;
  const int lm = lane & 15, lq = lane >> 4;
  const int sr = tid >> 1, sp = (tid & 1) * 16;
  f32x4 acc[4][4] = {};
  for (int k0 = 0; k0 < K; k0 += 32) {
    __syncthreads();
    const uint4* sa = (const uint4*)(A + (size_t)(row0 + sr) * K + k0 + sp);
    *(uint4*)&As[sr][sp] = sa[0];
    *(uint4*)&As[sr][sp + 8] = sa[1];
    const uint4* sb = (const uint4*)(Bt + (size_t)(col0 + sr) * K + k0 + sp);
    *(uint4*)&Bs[sr][sp] = sb[0];
    *(uint4*)&Bs[sr][sp + 8] = sb[1];
    __syncthreads();
    short8 af[4], bf[4];
#pragma unroll
    for (int i = 0; i < 4; i++) af[i] = *(const short8*)&As[wr * 64 + i * 16 + lm][lq * 8];
#pragma unroll
    for (int j = 0; j < 4; j++) bf[j] = *(const short8*)&Bs[wc * 64 + j * 16 + lm][lq * 8];
#pragma unroll
    for (int i = 0; i < 4; i++)
#pragma unroll
      for (int j = 0; j < 4; j++)
        acc[i][j] = __builtin_amdgcn_mfma_f32_16x16x32_bf16(af[i], bf[j], acc[i][j], 0, 0, 0);
  }
  float* Cb = C0;
  int cadj = 0;
  if (C1 && col0 >= split_col) { Cb = C1; cadj = split_col; }
#pragma unroll
  for (int i = 0; i < 4; i++) {
#pragma unroll
    for (int j = 0; j < 4; j++) {
      int col = col0 - cadj + wc * 64 + j * 16 + lm;
#pragma unroll
      for (int r = 0; r < 4; r++) {
        int row = row0 + wr * 64 + i * 16 + lq * 4 + r;
        float* cp = Cb + (size_t)row * ldc + col;
        if (ADD) *cp += acc[i][j][r];
        else *cp = acc[i][j][r];
      }
    }
  }
}

// ---------------- causal depthwise conv (K=4) + bias + SiLU ----------------
__global__ __launch_bounds__(256) void conv_silu_kernel(
    const float* __restrict__ xm, const float* __restrict__ cw, const float* __restrict__ cb,
    float* __restrict__ xc)
{
  int idx = blockIdx.x * 256 + threadIdx.x;
  int g = idx & 255;
  int row = idx >> 8;
  int s = row & (S_LEN - 1);
  int c0 = g * 4;
  const float* base = xm + (size_t)row * INNER_D + c0;
  float4 acc = {0.f, 0.f, 0.f, 0.f};
#pragma unroll
  for (int kk = 0; kk < 4; kk++) {
    int ts = s - 3 + kk;
    if (ts >= 0) {
      float4 xv = *(const float4*)(base + (ptrdiff_t)(kk - 3) * INNER_D);
      acc.x += xv.x * cw[(c0 + 0) * 4 + kk];
      acc.y += xv.y * cw[(c0 + 1) * 4 + kk];
      acc.z += xv.z * cw[(c0 + 2) * 4 + kk];
      acc.w += xv.w * cw[(c0 + 3) * 4 + kk];
    }
  }
  acc.x += cb[c0 + 0]; acc.y += cb[c0 + 1];
  acc.z += cb[c0 + 2]; acc.w += cb[c0 + 3];
  acc.x = acc.x / (1.f + __expf(-acc.x));
  acc.y = acc.y / (1.f + __expf(-acc.y));
  acc.z = acc.z / (1.f + __expf(-acc.z));
  acc.w = acc.w / (1.f + __expf(-acc.w));
  *(float4*)(xc + (size_t)row * INNER_D + c0) = acc;
}

// ---------------- headwise 4x4 projections ----------------
__global__ __launch_bounds__(256) void qkv_headwise_kernel(
    const float* __restrict__ xc, const float* __restrict__ xm,
    const float* __restrict__ qw, const float* __restrict__ kw, const float* __restrict__ vw,
    float* __restrict__ q, float* __restrict__ k, float* __restrict__ v)
{
  int idx = blockIdx.x * 256 + threadIdx.x;
  int g = idx & 255;
  size_t row = idx >> 8;
  float4 xc4 = *(const float4*)(xc + row * INNER_D + g * 4);
  float4 xm4 = *(const float4*)(xm + row * INNER_D + g * 4);
  const float* qg = qw + g * 16;
  const float* kg = kw + g * 16;
  const float* vg = vw + g * 16;
  float xcv[4] = {xc4.x, xc4.y, xc4.z, xc4.w};
  float xmv[4] = {xm4.x, xm4.y, xm4.z, xm4.w};
  float qo[4], ko[4], vo[4];
#pragma unroll
  for (int o = 0; o < 4; o++) {
    float aq = 0.f, ak = 0.f, av = 0.f;
#pragma unroll
    for (int d = 0; d < 4; d++) {
      aq += xcv[d] * qg[o * 4 + d];
      ak += xcv[d] * kg[o * 4 + d];
      av += xmv[d] * vg[o * 4 + d];
    }
    qo[o] = aq; ko[o] = ak; vo[o] = av;
  }
  float4 qs = {qo[0], qo[1], qo[2], qo[3]};
  float4 ks = {ko[0], ko[1], ko[2], ko[3]};
  float4 vs = {vo[0], vo[1], vo[2], vo[3]};
  *(float4*)(q + row * INNER_D + g * 4) = qs;
  *(float4*)(k + row * INNER_D + g * 4) = ks;
  *(float4*)(v + row * INNER_D + g * 4) = vs;
}

// ---------------- gate GEMVs ----------------
__global__ __launch_bounds__(256) void gates_kernel(
    const float* __restrict__ q, const float* __restrict__ k, const float* __restrict__ v,
    const float* __restrict__ igW, const float* __restrict__ igb,
    const float* __restrict__ fgW, const float* __restrict__ fgb,
    float* __restrict__ ig, float* __restrict__ fg)
{
  int row = blockIdx.x;
  int b = row >> 10, s = row & (S_LEN - 1);
  int tid = threadIdx.x;
  float ia[8] = {}, fa[8] = {};
#pragma unroll
  for (int i = 0; i < 12; i++) {
    int j = tid + i * 256;
    float xv;
    if (j < 1024) xv = q[(size_t)row * INNER_D + j];
    else if (j < 2048) xv = k[(size_t)row * INNER_D + j - 1024];
    else xv = v[(size_t)row * INNER_D + j - 2048];
    float4 wi0 = *(const float4*)(igW + (size_t)j * 8);
    float4 wi1 = *(const float4*)(igW + (size_t)j * 8 + 4);
    float4 wf0 = *(const float4*)(fgW + (size_t)j * 8);
    float4 wf1 = *(const float4*)(fgW + (size_t)j * 8 + 4);
    ia[0] += xv * wi0.x; ia[1] += xv * wi0.y; ia[2] += xv * wi0.z; ia[3] += xv * wi0.w;
    ia[4] += xv * wi1.x; ia[5] += xv * wi1.y; ia[6] += xv * wi1.z; ia[7] += xv * wi1.w;
    fa[0] += xv * wf0.x; fa[1] += xv * wf0.y; fa[2] += xv * wf0.z; fa[3] += xv * wf0.w;
    fa[4] += xv * wf1.x; fa[5] += xv * wf1.y; fa[6] += xv * wf1.z; fa[7] += xv * wf1.w;
  }
#pragma unroll
  for (int off = 32; off; off >>= 1) {
#pragma unroll
    for (int n = 0; n < 8; n++) {
      ia[n] += __shfl_xor(ia[n], off);
      fa[n] += __shfl_xor(fa[n], off);
    }
  }
  __shared__ float red[2][4][8];
  int wv = tid >> 6;
  if ((tid & 63) == 0) {
#pragma unroll
    for (int n = 0; n < 8; n++) { red[0][wv][n] = ia[n]; red[1][wv][n] = fa[n]; }
  }
  __syncthreads();
  if (tid < 8) {
    float si = red[0][0][tid] + red[0][1][tid] + red[0][2][tid] + red[0][3][tid];
    float sf = red[1][0][tid] + red[1][1][tid] + red[1][2][tid] + red[1][3][tid];
    size_t o = ((size_t)(b * NHEAD + tid) << 10) + s;
    ig[o] = si + igb[tid];
    fg[o] = sf + fgb[tid];
  }
}

// ---------------- per-(b,h) scans ----------------
__global__ __launch_bounds__(1024) void scan_kernel(
    const float* __restrict__ ig, const float* __restrict__ fg,
    float* __restrict__ a, float* __restrict__ rm, float* __restrict__ enm)
{
  int bh = blockIdx.x;
  int t = threadIdx.x;
  __shared__ float buf[1024];
  size_t o = ((size_t)bh << 10) + t;
  float f = fg[o];
  float lf = (f >= 0.f) ? -log1pf(__expf(-f)) : f - log1pf(__expf(f));
  buf[t] = lf;
  __syncthreads();
  float run = lf;
  for (int off = 1; off < 1024; off <<= 1) {
    float add = (t >= off) ? buf[t - off] : 0.f;
    __syncthreads();
    run += add;
    buf[t] = run;
    __syncthreads();
  }
  float cs = run;
  float av = ig[o] - cs;
  a[o] = av;
  buf[t] = av;
  __syncthreads();
  float rmx = av;
  for (int off = 1; off < 1024; off <<= 1) {
    float m = (t >= off) ? buf[t - off] : -3.4e38f;
    __syncthreads();
    rmx = fmaxf(rmx, m);
    buf[t] = rmx;
    __syncthreads();
  }
  rm[o] = rmx;
  enm[o] = __expf(-(cs + rmx));
}

// ---------------- fused tiled attention (round-5 structure + conflict-free maps), bf16 out ----------------
__global__ __launch_bounds__(256) void attn_tile_kernel(
    const float* __restrict__ q, const float* __restrict__ k, const float* __restrict__ v,
    const float* __restrict__ a_arr, const float* __restrict__ rm_arr, const float* __restrict__ enm_arr,
    const float* __restrict__ xc, const float* __restrict__ z,
    const float* __restrict__ skip, const float* __restrict__ onw,
    u16* __restrict__ hs)
{
  const int qt = blockIdx.x;    // 0..15
  const int bh = blockIdx.y;    // 0..15
  const int b = bh >> 3, h = bh & 7;
  const int s0 = qt * 64;
  const int tid = threadIdx.x;
  const int tx = tid & 15, ty = tid >> 4;
  const size_t rowbase = (size_t)b * S_LEN;
  const int c0 = h * DHEAD;

  __shared__ float Qs[64 * 132];
  __shared__ float KsW[64 * 132];  // K tile [col][d]; reused as w[64][68], then reductions
  __shared__ float Vs[64 * 132];
  __shared__ float as_[64];
  __shared__ float invn[64], mu_s[64], rs_s[64];

#pragma unroll
  for (int rep = 0; rep < 8; rep++) {
    int idx = rep * 256 + tid;
    int r = idx >> 5, f4 = idx & 31;
    *(float4*)&Qs[r * 132 + f4 * 4] =
        *(const float4*)(q + (rowbase + s0 + r) * INNER_D + c0 + f4 * 4);
  }
  float rmv[4];
#pragma unroll
  for (int i = 0; i < 4; i++) rmv[i] = rm_arr[(size_t)bh * S_LEN + s0 + ty * 4 + i];

  float accH[4][8] = {};
  float sc_part[4] = {0.f, 0.f, 0.f, 0.f};
  const float scale = 0.08838834764831845f;  // 1/sqrt(128)

  for (int kt = 0; kt <= qt; kt++) {
    const int t0 = kt * 64;
    __syncthreads();
#pragma unroll
    for (int rep = 0; rep < 8; rep++) {
      int idx = rep * 256 + tid;
      int r = idx >> 5, f4 = idx & 31;
      *(float4*)&KsW[r * 132 + f4 * 4] =
          *(const float4*)(k + (rowbase + t0 + r) * INNER_D + c0 + f4 * 4);
      *(float4*)&Vs[r * 132 + f4 * 4] =
          *(const float4*)(v + (rowbase + t0 + r) * INNER_D + c0 + f4 * 4);
    }
    if (tid < 64) as_[tid] = a_arr[(size_t)bh * S_LEN + t0 + tid];
    __syncthreads();

    // phase A: p[i][j] = Q[s0+ty*4+i] . K[t0 + j*16+tx]
    float p[4][4] = {};
    for (int d4 = 0; d4 < 32; d4++) {
      int d = d4 * 4;
      float4 qv[4], kv[4];
#pragma unroll
      for (int i = 0; i < 4; i++) qv[i] = *(const float4*)&Qs[(ty * 4 + i) * 132 + d];
#pragma unroll
      for (int j = 0; j < 4; j++) kv[j] = *(const float4*)&KsW[(j * 16 + tx) * 132 + d];
#pragma unroll
      for (int i = 0; i < 4; i++)
#pragma unroll
        for (int j = 0; j < 4; j++)
          p[i][j] += qv[i].x * kv[j].x + qv[i].y * kv[j].y + qv[i].z * kv[j].z + qv[i].w * kv[j].w;
    }
    __syncthreads();

    // w + causal mask + row-sum partials; w[row][col] stride 68
#pragma unroll
    for (int i = 0; i < 4; i++) {
      int sg = s0 + ty * 4 + i;
#pragma unroll
      for (int j = 0; j < 4; j++) {
        int cl = j * 16 + tx;
        float w = p[i][j] * scale * __expf(as_[cl] - rmv[i]);
        if (t0 + cl > sg) w = 0.f;
        sc_part[i] += w;
        KsW[(ty * 4 + i) * 68 + cl] = w;
      }
    }
    __syncthreads();

    // phase B: accH[i][0..3] -> cols tx*4.. ; accH[i][4..7] -> cols 64+tx*4..
    for (int c4 = 0; c4 < 16; c4++) {
      int c = c4 * 4;
      float wq[4][4];
#pragma unroll
      for (int i = 0; i < 4; i++) {
        float4 wr = *(const float4*)&KsW[(ty * 4 + i) * 68 + c];
        wq[i][0] = wr.x; wq[i][1] = wr.y; wq[i][2] = wr.z; wq[i][3] = wr.w;
      }
#pragma unroll
      for (int cj = 0; cj < 4; cj++) {
        float4 va = *(const float4*)&Vs[(c + cj) * 132 + tx * 4];
        float4 vb = *(const float4*)&Vs[(c + cj) * 132 + 64 + tx * 4];
#pragma unroll
        for (int i = 0; i < 4; i++) {
          float wf = wq[i][cj];
          accH[i][0] += wf * va.x; accH[i][1] += wf * va.y;
          accH[i][2] += wf * va.z; accH[i][3] += wf * va.w;
          accH[i][4] += wf * vb.x; accH[i][5] += wf * vb.y;
          accH[i][6] += wf * vb.z; accH[i][7] += wf * vb.w;
        }
      }
    }
  }
  __syncthreads();

  // row-sum reduction -> invn
#pragma unroll
  for (int i = 0; i < 4; i++) KsW[(ty * 4 + i) * 17 + tx] = sc_part[i];
  __syncthreads();
  if (tid < 64) {
    float ssum = 0.f;
#pragma unroll
    for (int t = 0; t < 16; t++) ssum += KsW[tid * 17 + t];
    float nrm = fmaxf(fabsf(ssum), enm_arr[(size_t)bh * S_LEN + s0 + tid]);
    invn[tid] = 1.f / (nrm + 1e-6f);
  }
  __syncthreads();
#pragma unroll
  for (int i = 0; i < 4; i++) {
    float inv = invn[ty * 4 + i];
    float s = 0.f, qq = 0.f;
#pragma unroll
    for (int dd = 0; dd < 8; dd++) {
      float hv = accH[i][dd] * inv;
      accH[i][dd] = hv;
      s += hv; qq += hv * hv;
    }
    KsW[1088 + (ty * 4 + i) * 17 + tx] = s;
    KsW[2176 + (ty * 4 + i) * 17 + tx] = qq;
  }
  __syncthreads();
  if (tid < 64) {
    float s = 0.f, qq = 0.f;
#pragma unroll
    for (int t = 0; t < 16; t++) { s += KsW[1088 + tid * 17 + t]; qq += KsW[2176 + tid * 17 + t]; }
    float mu = s * (1.f / DHEAD);
    float var = qq * (1.f / DHEAD) - mu * mu;
    mu_s[tid] = mu;
    rs_s[tid] = rsqrtf(var + 1e-5f);
  }
  __syncthreads();

  float4 owa = *(const float4*)(onw + c0 + tx * 4);
  float4 owb = *(const float4*)(onw + c0 + 64 + tx * 4);
  float4 ska = *(const float4*)(skip + c0 + tx * 4);
  float4 skb = *(const float4*)(skip + c0 + 64 + tx * 4);
#pragma unroll
  for (int i = 0; i < 4; i++) {
    int sg = s0 + ty * 4 + i;
    float mu = mu_s[ty * 4 + i], rs = rs_s[ty * 4 + i];
    size_t base = (rowbase + sg) * INNER_D + c0;
    float4 xca = *(const float4*)(xc + base + tx * 4);
    float4 xcb = *(const float4*)(xc + base + 64 + tx * 4);
    float4 za = *(const float4*)(z + base + tx * 4);
    float4 zb = *(const float4*)(z + base + 64 + tx * 4);
    float oa0 = ((accH[i][0] - mu) * rs * owa.x + ska.x * xca.x) * (za.x / (1.f + __expf(-za.x)));
    float oa1 = ((accH[i][1] - mu) * rs * owa.y + ska.y * xca.y) * (za.y / (1.f + __expf(-za.y)));
    float oa2 = ((accH[i][2] - mu) * rs * owa.z + ska.z * xca.z) * (za.z / (1.f + __expf(-za.z)));
    float oa3 = ((accH[i][3] - mu) * rs * owa.w + ska.w * xca.w) * (za.w / (1.f + __expf(-za.w)));
    float ob0 = ((accH[i][4] - mu) * rs * owb.x + skb.x * xcb.x) * (zb.x / (1.f + __expf(-zb.x)));
    float ob1 = ((accH[i][5] - mu) * rs * owb.y + skb.y * xcb.y) * (zb.y / (1.f + __expf(-zb.y)));
    float ob2 = ((accH[i][6] - mu) * rs * owb.z + skb.z * xcb.z) * (zb.z / (1.f + __expf(-zb.z)));
    float ob3 = ((accH[i][7] - mu) * rs * owb.w + skb.w * xcb.w) * (zb.w / (1.f + __expf(-zb.w)));
    ushort4 ua, ub;
    ua.x = f2bf(oa0); ua.y = f2bf(oa1); ua.z = f2bf(oa2); ua.w = f2bf(oa3);
    ub.x = f2bf(ob0); ub.y = f2bf(ob1); ub.z = f2bf(ob2); ub.w = f2bf(ob3);
    *(ushort4*)(hs + base + tx * 4) = ua;
    *(ushort4*)(hs + base + 64 + tx * 4) = ub;
  }
}

// ---------------- head ----------------
__global__ __launch_bounds__(64) void head_kernel(
    const float* __restrict__ ln96, const float* __restrict__ hW, const float* __restrict__ hb,
    float* __restrict__ out)
{
  int row = blockIdx.x;
  int n = threadIdx.x;
  if (n >= 21) return;
  float acc = hb[n];
  const float* xr = ln96 + (size_t)row * E_DIM;
  for (int kk = 0; kk < E_DIM; kk++) acc += xr[kk] * hW[kk * 21 + n];
  out[row * 21 + n] = acc;
}

extern "C" void kernel_launch(void* const* d_in, const int* in_sizes, int n_in,
                              void* d_out, int out_size, void* d_ws, size_t ws_size,
                              hipStream_t stream)
{
  const float* x_enc   = (const float*)d_in[0];
  const float* x_mark  = (const float*)d_in[1];
  const float* emb_W   = (const float*)d_in[4];
  const float* emb_b   = (const float*)d_in[5];
  const float* ln_w    = (const float*)d_in[6];
  const float* up_W    = (const float*)d_in[7];
  const float* conv_W  = (const float*)d_in[8];
  const float* conv_b  = (const float*)d_in[9];
  const float* q_W     = (const float*)d_in[10];
  const float* k_W     = (const float*)d_in[11];
  const float* v_W     = (const float*)d_in[12];
  const float* ig_W    = (const float*)d_in[13];
  const float* ig_b    = (const float*)d_in[14];
  const float* fg_W    = (const float*)d_in[15];
  const float* fg_b    = (const float*)d_in[16];
  const float* skip_w  = (const float*)d_in[17];
  const float* onorm_w = (const float*)d_in[18];
  const float* down_W  = (const float*)d_in[19];
  const float* post_ln = (const float*)d_in[20];
  const float* head_W  = (const float*)d_in[21];
  const float* head_b  = (const float*)d_in[22];

  float* p = (float*)d_ws;
  float* x    = p; p += 1048576;   // 2048*512 f32
  float* xm   = p; p += 2097152;   // 2048*1024 f32 (reused as hsbh bf16 after qkv)
  float* z    = p; p += 2097152;
  float* xc   = p; p += 2097152;
  float* qb   = p; p += 2097152;
  float* kb   = p; p += 2097152;
  float* vb   = p; p += 2097152;
  float* igb_ = p; p += 16384;
  float* fgb_ = p; p += 16384;
  float* ab   = p; p += 16384;
  float* rmb  = p; p += 16384;
  float* enmb = p; p += 16384;
  float* ln96 = p; p += 98304;
  u16* xnh  = (u16*)p; p += 524288;   // 2048*512 bf16
  u16* upWt = (u16*)p; p += 524288;   // 2048*512 bf16 (per-layer, reused)
  u16* dnWt = (u16*)p; p += 262144;   // 512*1024 bf16 (per-layer, reused)
  u16* hsbh = (u16*)xm;               // 2048*1024 bf16, aliases xm (dead after qkv)

  embed_kernel<<<2048, 128, 0, stream>>>(x_enc, x_mark, emb_W, emb_b, x);

  for (int L = 0; L < 4; L++) {
    ln_kernel<<<2048, 256, 0, stream>>>(x, ln_w + L * 512, xnh);
    transpose_bf16_kernel<<<dim3(8, 32), 256, 0, stream>>>(
        up_W + (size_t)L * 512 * 2048, upWt, 512, 2048);
    gemm_bf16<0><<<dim3(16, 16), 256, 0, stream>>>(
        xnh, upWt, xm, z, 2048, 2048, 512, 1024, 1024);
    conv_silu_kernel<<<2048, 256, 0, stream>>>(xm, conv_W + L * 4096, conv_b + L * 1024, xc);
    qkv_headwise_kernel<<<2048, 256, 0, stream>>>(
        xc, xm, q_W + L * 4096, k_W + L * 4096, v_W + L * 4096, qb, kb, vb);
    gates_kernel<<<2048, 256, 0, stream>>>(
        qb, kb, vb, ig_W + L * 24576, ig_b + L * 8, fg_W + L * 24576, fg_b + L * 8, igb_, fgb_);
    scan_kernel<<<16, 1024, 0, stream>>>(igb_, fgb_, ab, rmb, enmb);
    attn_tile_kernel<<<dim3(16, 16), 256, 0, stream>>>(
        qb, kb, vb, ab, rmb, enmb, xc, z, skip_w + L * 1024, onorm_w + L * 1024, hsbh);
    transpose_bf16_kernel<<<dim3(16, 8), 256, 0, stream>>>(
        down_W + (size_t)L * 1024 * 512, dnWt, 1024, 512);
    gemm_bf16<1><<<dim3(4, 16), 256, 0, stream>>>(
        hsbh, dnWt, x, nullptr, 2048, 512, 1024, 1 << 30, 512);
  }

  ln_final_kernel<<<192, 256, 0, stream>>>(x, post_ln, ln96);
  head_kernel<<<192, 64, 0, stream>>>(ln96, head_W, head_b, (float*)d_out);
}

// Round 9
// 942.611 us; speedup vs baseline: 2.0428x; 1.4009x over previous
//
#include <hip/hip_runtime.h>
#include <hip/hip_bf16.h>

#define S_LEN 1024
#define E_DIM 512
#define INNER_D 1024
#define NHEAD 8
#define DHEAD 128

typedef unsigned short u16;
typedef unsigned int u32;
typedef __attribute__((ext_vector_type(8))) short short8;
typedef __attribute__((ext_vector_type(4))) float f32x4;

union S8 { short8 v; u16 u[8]; uint2 p[2]; };

__device__ __forceinline__ u16 f2bf(float f) {
  u32 u = __float_as_uint(f);
  u32 r = u + 0x7FFFu + ((u >> 16) & 1u);
  return (u16)(r >> 16);
}
__device__ __forceinline__ float bf2f(u16 u) { return __uint_as_float(((u32)u) << 16); }
__device__ __forceinline__ void split2(float f, u16& hi, u16& lo) {
  hi = f2bf(f);
  lo = f2bf(f - bf2f(hi));
}

// ---------------- embedding ----------------
__global__ __launch_bounds__(128) void embed_kernel(
    const float* __restrict__ xe, const float* __restrict__ xm,
    const float* __restrict__ W, const float* __restrict__ bias,
    float* __restrict__ x)
{
  int row = blockIdx.x;
  int tid = threadIdx.x;
  __shared__ float in_s[25];
  if (tid < 21) in_s[tid] = xe[row * 21 + tid];
  else if (tid < 25) in_s[tid] = xm[row * 4 + tid - 21];
  __syncthreads();
#pragma unroll
  for (int rep = 0; rep < 4; rep++) {
    int e = tid + rep * 128;
    float acc = bias[e];
#pragma unroll
    for (int i = 0; i < 25; i++) acc += in_s[i] * W[i * E_DIM + e];
    x[(size_t)row * E_DIM + e] = acc;
  }
}

// ---------------- layernorm -> bf16 ----------------
__global__ __launch_bounds__(256) void ln_kernel(
    const float* __restrict__ x, const float* __restrict__ w, u16* __restrict__ out)
{
  int row = blockIdx.x, tid = threadIdx.x;
  const float* xr = x + (size_t)row * E_DIM;
  float2 v = *(const float2*)(xr + tid * 2);
  float s = v.x + v.y, q = v.x * v.x + v.y * v.y;
#pragma unroll
  for (int off = 32; off; off >>= 1) { s += __shfl_xor(s, off); q += __shfl_xor(q, off); }
  __shared__ float ssum[4], ssq[4];
  int wv = tid >> 6;
  if ((tid & 63) == 0) { ssum[wv] = s; ssq[wv] = q; }
  __syncthreads();
  s = ssum[0] + ssum[1] + ssum[2] + ssum[3];
  q = ssq[0] + ssq[1] + ssq[2] + ssq[3];
  float mu = s * (1.f / E_DIM);
  float var = q * (1.f / E_DIM) - mu * mu;
  float rs = rsqrtf(var + 1e-5f);
  int e = tid * 2;
  ushort2 o;
  o.x = f2bf((v.x - mu) * rs * w[e]);
  o.y = f2bf((v.y - mu) * rs * w[e + 1]);
  *(ushort2*)(out + (size_t)row * E_DIM + e) = o;
}

__global__ __launch_bounds__(256) void ln_final_kernel(
    const float* __restrict__ x, const float* __restrict__ w, float* __restrict__ out)
{
  int ridx = blockIdx.x;
  int b = ridx / 96, r = ridx % 96;
  int row = b * S_LEN + (S_LEN - 96) + r;
  int tid = threadIdx.x;
  const float* xr = x + (size_t)row * E_DIM;
  float2 v = *(const float2*)(xr + tid * 2);
  float s = v.x + v.y, q = v.x * v.x + v.y * v.y;
#pragma unroll
  for (int off = 32; off; off >>= 1) { s += __shfl_xor(s, off); q += __shfl_xor(q, off); }
  __shared__ float ssum[4], ssq[4];
  int wv = tid >> 6;
  if ((tid & 63) == 0) { ssum[wv] = s; ssq[wv] = q; }
  __syncthreads();
  s = ssum[0] + ssum[1] + ssum[2] + ssum[3];
  q = ssq[0] + ssq[1] + ssq[2] + ssq[3];
  float mu = s * (1.f / E_DIM);
  float var = q * (1.f / E_DIM) - mu * mu;
  float rs = rsqrtf(var + 1e-5f);
  int e = tid * 2;
  float2 o;
  o.x = (v.x - mu) * rs * w[e];
  o.y = (v.y - mu) * rs * w[e + 1];
  *(float2*)(out + (size_t)ridx * E_DIM + e) = o;
}

// ---------------- transpose f32 [K][N] -> bf16 [N][K] ----------------
__global__ __launch_bounds__(256) void transpose_bf16_kernel(
    const float* __restrict__ in, u16* __restrict__ out, int K, int N)
{
  __shared__ u16 T[64][72];
  int k0 = blockIdx.x * 64, n0 = blockIdx.y * 64;
  int t = threadIdx.x;
  int kr = t >> 2, nseg = (t & 3) * 16;
  const float* src = in + (size_t)(k0 + kr) * N + n0 + nseg;
#pragma unroll
  for (int j = 0; j < 16; j++) T[kr][nseg + j] = f2bf(src[j]);
  __syncthreads();
  int nr = t >> 2, kseg = (t & 3) * 16;
  u32 u[8];
#pragma unroll
  for (int rr = 0; rr < 8; rr++) {
    u32 lo = T[kseg + 2 * rr][nr];
    u32 hi = T[kseg + 2 * rr + 1][nr];
    u[rr] = lo | (hi << 16);
  }
  u16* dst = out + (size_t)(n0 + nr) * K + k0 + kseg;
  uint4 w0 = {u[0], u[1], u[2], u[3]};
  uint4 w1 = {u[4], u[5], u[6], u[7]};
  *(uint4*)dst = w0;
  *(uint4*)(dst + 8) = w1;
}

// ---------------- bf16 MFMA GEMM: C[M,N] (+)= A[M,K] @ Bt[N,K]^T ----------------
template <int ADD>
__global__ __launch_bounds__(256) void gemm_bf16(
    const u16* __restrict__ A, const u16* __restrict__ Bt,
    float* __restrict__ C0, float* __restrict__ C1,
    int M, int N, int K, int split_col, int ldc)
{
  __shared__ u16 As[128][40];
  __shared__ u16 Bs[128][40];
  const int tid = threadIdx.x;
  const int row0 = blockIdx.y * 128, col0 = blockIdx.x * 128;
  const int wave = tid >> 6, lane = tid & 63;
  const int wr = wave >> 1, wc = wave & 1;
  const int lm = lane & 15, lq = lane >> 4;
  const int sr = tid >> 1, sp = (tid & 1) * 16;
  f32x4 acc[4][4] = {};
  for (int k0 = 0; k0 < K; k0 += 32) {
    __syncthreads();
    const uint4* sa = (const uint4*)(A + (size_t)(row0 + sr) * K + k0 + sp);
    *(uint4*)&As[sr][sp] = sa[0];
    *(uint4*)&As[sr][sp + 8] = sa[1];
    const uint4* sb = (const uint4*)(Bt + (size_t)(col0 + sr) * K + k0 + sp);
    *(uint4*)&Bs[sr][sp] = sb[0];
    *(uint4*)&Bs[sr][sp + 8] = sb[1];
    __syncthreads();
    short8 af[4], bf[4];
#pragma unroll
    for (int i = 0; i < 4; i++) af[i] = *(const short8*)&As[wr * 64 + i * 16 + lm][lq * 8];
#pragma unroll
    for (int j = 0; j < 4; j++) bf[j] = *(const short8*)&Bs[wc * 64 + j * 16 + lm][lq * 8];
#pragma unroll
    for (int i = 0; i < 4; i++)
#pragma unroll
      for (int j = 0; j < 4; j++)
        acc[i][j] = __builtin_amdgcn_mfma_f32_16x16x32_bf16(af[i], bf[j], acc[i][j], 0, 0, 0);
  }
  float* Cb = C0;
  int cadj = 0;
  if (C1 && col0 >= split_col) { Cb = C1; cadj = split_col; }
#pragma unroll
  for (int i = 0; i < 4; i++) {
#pragma unroll
    for (int j = 0; j < 4; j++) {
      int col = col0 - cadj + wc * 64 + j * 16 + lm;
#pragma unroll
      for (int r = 0; r < 4; r++) {
        int row = row0 + wr * 64 + i * 16 + lq * 4 + r;
        float* cp = Cb + (size_t)row * ldc + col;
        if (ADD) *cp += acc[i][j][r];
        else *cp = acc[i][j][r];
      }
    }
  }
}

// ---------------- causal depthwise conv (K=4) + bias + SiLU ----------------
__global__ __launch_bounds__(256) void conv_silu_kernel(
    const float* __restrict__ xm, const float* __restrict__ cw, const float* __restrict__ cb,
    float* __restrict__ xc)
{
  int idx = blockIdx.x * 256 + threadIdx.x;
  int g = idx & 255;
  int row = idx >> 8;
  int s = row & (S_LEN - 1);
  int c0 = g * 4;
  const float* base = xm + (size_t)row * INNER_D + c0;
  float4 acc = {0.f, 0.f, 0.f, 0.f};
#pragma unroll
  for (int kk = 0; kk < 4; kk++) {
    int ts = s - 3 + kk;
    if (ts >= 0) {
      float4 xv = *(const float4*)(base + (ptrdiff_t)(kk - 3) * INNER_D);
      acc.x += xv.x * cw[(c0 + 0) * 4 + kk];
      acc.y += xv.y * cw[(c0 + 1) * 4 + kk];
      acc.z += xv.z * cw[(c0 + 2) * 4 + kk];
      acc.w += xv.w * cw[(c0 + 3) * 4 + kk];
    }
  }
  acc.x += cb[c0 + 0]; acc.y += cb[c0 + 1];
  acc.z += cb[c0 + 2]; acc.w += cb[c0 + 3];
  acc.x = acc.x / (1.f + __expf(-acc.x));
  acc.y = acc.y / (1.f + __expf(-acc.y));
  acc.z = acc.z / (1.f + __expf(-acc.z));
  acc.w = acc.w / (1.f + __expf(-acc.w));
  *(float4*)(xc + (size_t)row * INNER_D + c0) = acc;
}

// ---------------- headwise 4x4 projections -> hi/lo bf16 q,k,v ----------------
__global__ __launch_bounds__(256) void qkv_headwise_kernel(
    const float* __restrict__ xc, const float* __restrict__ xm,
    const float* __restrict__ qw, const float* __restrict__ kw, const float* __restrict__ vw,
    u16* __restrict__ qh, u16* __restrict__ ql,
    u16* __restrict__ kh, u16* __restrict__ kl,
    u16* __restrict__ vh, u16* __restrict__ vl)
{
  int idx = blockIdx.x * 256 + threadIdx.x;
  int g = idx & 255;
  size_t row = idx >> 8;
  float4 xc4 = *(const float4*)(xc + row * INNER_D + g * 4);
  float4 xm4 = *(const float4*)(xm + row * INNER_D + g * 4);
  const float* qg = qw + g * 16;
  const float* kg = kw + g * 16;
  const float* vg = vw + g * 16;
  float xcv[4] = {xc4.x, xc4.y, xc4.z, xc4.w};
  float xmv[4] = {xm4.x, xm4.y, xm4.z, xm4.w};
  ushort4 qhi, qlo, khi, klo, vhi, vlo;
  u16* qhp = (u16*)&qhi; u16* qlp = (u16*)&qlo;
  u16* khp = (u16*)&khi; u16* klp = (u16*)&klo;
  u16* vhp = (u16*)&vhi; u16* vlp = (u16*)&vlo;
#pragma unroll
  for (int o = 0; o < 4; o++) {
    float aq = 0.f, ak = 0.f, av = 0.f;
#pragma unroll
    for (int d = 0; d < 4; d++) {
      aq += xcv[d] * qg[o * 4 + d];
      ak += xcv[d] * kg[o * 4 + d];
      av += xmv[d] * vg[o * 4 + d];
    }
    split2(aq, qhp[o], qlp[o]);
    split2(ak, khp[o], klp[o]);
    split2(av, vhp[o], vlp[o]);
  }
  size_t off = row * INNER_D + g * 4;
  *(ushort4*)(qh + off) = qhi; *(ushort4*)(ql + off) = qlo;
  *(ushort4*)(kh + off) = khi; *(ushort4*)(kl + off) = klo;
  *(ushort4*)(vh + off) = vhi; *(ushort4*)(vl + off) = vlo;
}

// ---------------- gate GEMVs (hi+lo reconstruct = fp32-exact) ----------------
__global__ __launch_bounds__(256) void gates_kernel(
    const u16* __restrict__ qh, const u16* __restrict__ ql,
    const u16* __restrict__ kh, const u16* __restrict__ kl,
    const u16* __restrict__ vh, const u16* __restrict__ vl,
    const float* __restrict__ igW, const float* __restrict__ igb,
    const float* __restrict__ fgW, const float* __restrict__ fgb,
    float* __restrict__ ig, float* __restrict__ fg)
{
  int row = blockIdx.x;
  int b = row >> 10, s = row & (S_LEN - 1);
  int tid = threadIdx.x;
  float ia[8] = {}, fa[8] = {};
#pragma unroll
  for (int i = 0; i < 12; i++) {
    int j = tid + i * 256;
    float xv;
    if (j < 1024) {
      size_t o = (size_t)row * INNER_D + j;
      xv = bf2f(qh[o]) + bf2f(ql[o]);
    } else if (j < 2048) {
      size_t o = (size_t)row * INNER_D + j - 1024;
      xv = bf2f(kh[o]) + bf2f(kl[o]);
    } else {
      size_t o = (size_t)row * INNER_D + j - 2048;
      xv = bf2f(vh[o]) + bf2f(vl[o]);
    }
    float4 wi0 = *(const float4*)(igW + (size_t)j * 8);
    float4 wi1 = *(const float4*)(igW + (size_t)j * 8 + 4);
    float4 wf0 = *(const float4*)(fgW + (size_t)j * 8);
    float4 wf1 = *(const float4*)(fgW + (size_t)j * 8 + 4);
    ia[0] += xv * wi0.x; ia[1] += xv * wi0.y; ia[2] += xv * wi0.z; ia[3] += xv * wi0.w;
    ia[4] += xv * wi1.x; ia[5] += xv * wi1.y; ia[6] += xv * wi1.z; ia[7] += xv * wi1.w;
    fa[0] += xv * wf0.x; fa[1] += xv * wf0.y; fa[2] += xv * wf0.z; fa[3] += xv * wf0.w;
    fa[4] += xv * wf1.x; fa[5] += xv * wf1.y; fa[6] += xv * wf1.z; fa[7] += xv * wf1.w;
  }
#pragma unroll
  for (int off = 32; off; off >>= 1) {
#pragma unroll
    for (int n = 0; n < 8; n++) {
      ia[n] += __shfl_xor(ia[n], off);
      fa[n] += __shfl_xor(fa[n], off);
    }
  }
  __shared__ float red[2][4][8];
  int wv = tid >> 6;
  if ((tid & 63) == 0) {
#pragma unroll
    for (int n = 0; n < 8; n++) { red[0][wv][n] = ia[n]; red[1][wv][n] = fa[n]; }
  }
  __syncthreads();
  if (tid < 8) {
    float si = red[0][0][tid] + red[0][1][tid] + red[0][2][tid] + red[0][3][tid];
    float sf = red[1][0][tid] + red[1][1][tid] + red[1][2][tid] + red[1][3][tid];
    size_t o = ((size_t)(b * NHEAD + tid) << 10) + s;
    ig[o] = si + igb[tid];
    fg[o] = sf + fgb[tid];
  }
}

// ---------------- per-(b,h) scans ----------------
__global__ __launch_bounds__(1024) void scan_kernel(
    const float* __restrict__ ig, const float* __restrict__ fg,
    float* __restrict__ a, float* __restrict__ rm, float* __restrict__ enm)
{
  int bh = blockIdx.x;
  int t = threadIdx.x;
  __shared__ float buf[1024];
  size_t o = ((size_t)bh << 10) + t;
  float f = fg[o];
  float lf = (f >= 0.f) ? -log1pf(__expf(-f)) : f - log1pf(__expf(f));
  buf[t] = lf;
  __syncthreads();
  float run = lf;
  for (int off = 1; off < 1024; off <<= 1) {
    float add = (t >= off) ? buf[t - off] : 0.f;
    __syncthreads();
    run += add;
    buf[t] = run;
    __syncthreads();
  }
  float cs = run;
  float av = ig[o] - cs;
  a[o] = av;
  buf[t] = av;
  __syncthreads();
  float rmx = av;
  for (int off = 1; off < 1024; off <<= 1) {
    float m = (t >= off) ? buf[t - off] : -3.4e38f;
    __syncthreads();
    rmx = fmaxf(rmx, m);
    buf[t] = rmx;
    __syncthreads();
  }
  rm[o] = rmx;
  enm[o] = __expf(-(cs + rmx));
}

// ---------------- MFMA attention, hi/lo split-bf16 for fp32-class accuracy ----------------
__global__ __launch_bounds__(256) void attn_mfma_kernel(
    const u16* __restrict__ qhg, const u16* __restrict__ qlg,
    const u16* __restrict__ khg, const u16* __restrict__ klg,
    const u16* __restrict__ vhg, const u16* __restrict__ vlg,
    const float* __restrict__ a_arr, const float* __restrict__ rm_arr, const float* __restrict__ enm_arr,
    const float* __restrict__ xc, const float* __restrict__ z,
    const float* __restrict__ skip, const float* __restrict__ onw,
    u16* __restrict__ hs)
{
  const int qt = blockIdx.x;    // 0..15
  const int bh = blockIdx.y;    // 0..15
  const int b = bh >> 3, h = bh & 7;
  const int s0 = qt * 64;
  const int tid = threadIdx.x;
  const int wave = tid >> 6, lane = tid & 63;
  const int lm = lane & 15, lq = lane >> 4;
  const size_t rowbase = (size_t)b * S_LEN;
  const int c0 = h * DHEAD;

  __shared__ u16 Qh[64 * 136], Ql[64 * 136];
  __shared__ u16 Kh[64 * 136], Kl[64 * 136];
  __shared__ u16 Vth[128 * 68], Vtl[128 * 68];
  __shared__ u16 Wh[64 * 72], Wl[64 * 72];
  __shared__ float as_[64];

  // stage Q hi/lo
#pragma unroll
  for (int rep = 0; rep < 4; rep++) {
    int idx = rep * 256 + tid;
    int r = idx >> 4, seg = (idx & 15) * 8;
    size_t goff = (rowbase + s0 + r) * INNER_D + c0 + seg;
    *(uint4*)&Qh[r * 136 + seg] = *(const uint4*)(qhg + goff);
    *(uint4*)&Ql[r * 136 + seg] = *(const uint4*)(qlg + goff);
  }
  float rmv[4];
#pragma unroll
  for (int r = 0; r < 4; r++)
    rmv[r] = rm_arr[(size_t)bh * S_LEN + s0 + wave * 16 + lq * 4 + r];

  f32x4 accH[8] = {};
  float sc_acc[4] = {0.f, 0.f, 0.f, 0.f};
  const float scale = 0.08838834764831845f;  // 1/sqrt(128)

  for (int kt = 0; kt <= qt; kt++) {
    const int t0 = kt * 64;
    __syncthreads();
#pragma unroll
    for (int rep = 0; rep < 4; rep++) {
      int idx = rep * 256 + tid;
      int r = idx >> 4, seg = (idx & 15) * 8;
      size_t goff = (rowbase + t0 + r) * INNER_D + c0 + seg;
      *(uint4*)&Kh[r * 136 + seg] = *(const uint4*)(khg + goff);
      *(uint4*)&Kl[r * 136 + seg] = *(const uint4*)(klg + goff);
    }
#pragma unroll
    for (int rep = 0; rep < 16; rep++) {
      int idx = rep * 256 + tid;
      int dp = idx & 63, t = idx >> 6;
      size_t goff = (rowbase + t0 + t) * INNER_D + c0 + 2 * dp;
      u32 ph = *(const u32*)(vhg + goff);
      u32 pl = *(const u32*)(vlg + goff);
      Vth[(2 * dp) * 68 + t] = (u16)(ph & 0xffffu);
      Vth[(2 * dp + 1) * 68 + t] = (u16)(ph >> 16);
      Vtl[(2 * dp) * 68 + t] = (u16)(pl & 0xffffu);
      Vtl[(2 * dp + 1) * 68 + t] = (u16)(pl >> 16);
    }
    if (tid < 64) as_[tid] = a_arr[(size_t)bh * S_LEN + t0 + tid];
    __syncthreads();

    // phase A: p = qh*kh + ql*kh + qh*kl
    f32x4 pacc[4] = {};
#pragma unroll
    for (int kc = 0; kc < 4; kc++) {
      short8 aqh = *(const short8*)&Qh[(wave * 16 + lm) * 136 + kc * 32 + lq * 8];
      short8 aql = *(const short8*)&Ql[(wave * 16 + lm) * 136 + kc * 32 + lq * 8];
#pragma unroll
      for (int cb = 0; cb < 4; cb++) {
        short8 bkh = *(const short8*)&Kh[(cb * 16 + lm) * 136 + kc * 32 + lq * 8];
        short8 bkl = *(const short8*)&Kl[(cb * 16 + lm) * 136 + kc * 32 + lq * 8];
        pacc[cb] = __builtin_amdgcn_mfma_f32_16x16x32_bf16(aqh, bkh, pacc[cb], 0, 0, 0);
        pacc[cb] = __builtin_amdgcn_mfma_f32_16x16x32_bf16(aql, bkh, pacc[cb], 0, 0, 0);
        pacc[cb] = __builtin_amdgcn_mfma_f32_16x16x32_bf16(aqh, bkl, pacc[cb], 0, 0, 0);
      }
    }

    // w = p*scale*exp(a[t]-rm[s]) + causal mask; split hi/lo into Wh/Wl; rowsum fp32
    float wpart[4] = {0.f, 0.f, 0.f, 0.f};
#pragma unroll
    for (int cb = 0; cb < 4; cb++) {
      int colg = t0 + cb * 16 + lm;
      float ea = as_[cb * 16 + lm];
#pragma unroll
      for (int r = 0; r < 4; r++) {
        int rowg = s0 + wave * 16 + lq * 4 + r;
        float wv = pacc[cb][r] * scale * __expf(ea - rmv[r]);
        if (colg > rowg) wv = 0.f;
        wpart[r] += wv;
        int widx = (wave * 16 + lq * 4 + r) * 72 + cb * 16 + lm;
        u16 whh; u16 wll;
        split2(wv, whh, wll);
        Wh[widx] = whh;
        Wl[widx] = wll;
      }
    }
#pragma unroll
    for (int r = 0; r < 4; r++) {
      float sr = wpart[r];
      sr += __shfl_xor(sr, 1); sr += __shfl_xor(sr, 2);
      sr += __shfl_xor(sr, 4); sr += __shfl_xor(sr, 8);
      sc_acc[r] += sr;
    }

    // phase B: H += wh*vh + wl*vh + wh*vl
#pragma unroll
    for (int kc = 0; kc < 2; kc++) {
      short8 awh = *(const short8*)&Wh[(wave * 16 + lm) * 72 + kc * 32 + lq * 8];
      short8 awl = *(const short8*)&Wl[(wave * 16 + lm) * 72 + kc * 32 + lq * 8];
#pragma unroll
      for (int nb = 0; nb < 8; nb++) {
        S8 bvh, bvl;
        const u16* vph = &Vth[(nb * 16 + lm) * 68 + kc * 32 + lq * 8];
        const u16* vpl = &Vtl[(nb * 16 + lm) * 68 + kc * 32 + lq * 8];
        bvh.p[0] = *(const uint2*)vph; bvh.p[1] = *(const uint2*)(vph + 4);
        bvl.p[0] = *(const uint2*)vpl; bvl.p[1] = *(const uint2*)(vpl + 4);
        accH[nb] = __builtin_amdgcn_mfma_f32_16x16x32_bf16(awh, bvh.v, accH[nb], 0, 0, 0);
        accH[nb] = __builtin_amdgcn_mfma_f32_16x16x32_bf16(awl, bvh.v, accH[nb], 0, 0, 0);
        accH[nb] = __builtin_amdgcn_mfma_f32_16x16x32_bf16(awh, bvl.v, accH[nb], 0, 0, 0);
      }
    }
  }

  // norm + headwise LN (register/shuffle only)
  float inv[4], muv[4], rsv[4];
#pragma unroll
  for (int r = 0; r < 4; r++) {
    int rowg = s0 + wave * 16 + lq * 4 + r;
    float nrm = fmaxf(fabsf(sc_acc[r]), enm_arr[(size_t)bh * S_LEN + rowg]);
    inv[r] = 1.f / (nrm + 1e-6f);
  }
#pragma unroll
  for (int r = 0; r < 4; r++) {
    float s = 0.f, qq = 0.f;
#pragma unroll
    for (int nb = 0; nb < 8; nb++) {
      float hv = accH[nb][r] * inv[r];
      accH[nb][r] = hv;
      s += hv; qq += hv * hv;
    }
    s += __shfl_xor(s, 1); s += __shfl_xor(s, 2); s += __shfl_xor(s, 4); s += __shfl_xor(s, 8);
    qq += __shfl_xor(qq, 1); qq += __shfl_xor(qq, 2); qq += __shfl_xor(qq, 4); qq += __shfl_xor(qq, 8);
    float mu = s * (1.f / DHEAD);
    float var = qq * (1.f / DHEAD) - mu * mu;
    muv[r] = mu;
    rsv[r] = rsqrtf(var + 1e-5f);
  }

  // epilogue
  float ow[8], sk[8];
#pragma unroll
  for (int nb = 0; nb < 8; nb++) {
    ow[nb] = onw[c0 + nb * 16 + lm];
    sk[nb] = skip[c0 + nb * 16 + lm];
  }
#pragma unroll
  for (int r = 0; r < 4; r++) {
    int rowg = s0 + wave * 16 + lq * 4 + r;
    size_t base = (rowbase + rowg) * INNER_D + c0;
#pragma unroll
    for (int nb = 0; nb < 8; nb++) {
      int d = nb * 16 + lm;
      float xcv = xc[base + d];
      float zv = z[base + d];
      float hn = (accH[nb][r] - muv[r]) * rsv[r] * ow[nb] + sk[nb] * xcv;
      float o = hn * (zv / (1.f + __expf(-zv)));
      hs[base + d] = f2bf(o);
    }
  }
}

// ---------------- head ----------------
__global__ __launch_bounds__(64) void head_kernel(
    const float* __restrict__ ln96, const float* __restrict__ hW, const float* __restrict__ hb,
    float* __restrict__ out)
{
  int row = blockIdx.x;
  int n = threadIdx.x;
  if (n >= 21) return;
  float acc = hb[n];
  const float* xr = ln96 + (size_t)row * E_DIM;
  for (int kk = 0; kk < E_DIM; kk++) acc += xr[kk] * hW[kk * 21 + n];
  out[row * 21 + n] = acc;
}

extern "C" void kernel_launch(void* const* d_in, const int* in_sizes, int n_in,
                              void* d_out, int out_size, void* d_ws, size_t ws_size,
                              hipStream_t stream)
{
  const float* x_enc   = (const float*)d_in[0];
  const float* x_mark  = (const float*)d_in[1];
  const float* emb_W   = (const float*)d_in[4];
  const float* emb_b   = (const float*)d_in[5];
  const float* ln_w    = (const float*)d_in[6];
  const float* up_W    = (const float*)d_in[7];
  const float* conv_W  = (const float*)d_in[8];
  const float* conv_b  = (const float*)d_in[9];
  const float* q_W     = (const float*)d_in[10];
  const float* k_W     = (const float*)d_in[11];
  const float* v_W     = (const float*)d_in[12];
  const float* ig_W    = (const float*)d_in[13];
  const float* ig_b    = (const float*)d_in[14];
  const float* fg_W    = (const float*)d_in[15];
  const float* fg_b    = (const float*)d_in[16];
  const float* skip_w  = (const float*)d_in[17];
  const float* onorm_w = (const float*)d_in[18];
  const float* down_W  = (const float*)d_in[19];
  const float* post_ln = (const float*)d_in[20];
  const float* head_W  = (const float*)d_in[21];
  const float* head_b  = (const float*)d_in[22];

  // Workspace layout (floats). Sizes CORRECT this time:
  //   u16 buffer of E elements needs (E+1)/2 floats.
  float* p = (float*)d_ws;
  float* x    = p; p += 1048576;   // 2048*512 f32
  float* xm   = p; p += 2097152;   // 2048*1024 f32; reused as hsbh (bf16) after qkv
  float* z    = p; p += 2097152;
  float* xc   = p; p += 2097152;
  float* igb_ = p; p += 16384;
  float* fgb_ = p; p += 16384;
  float* ab   = p; p += 16384;
  float* rmb  = p; p += 16384;
  float* enmb = p; p += 16384;
  float* ln96 = p; p += 98304;
  u16* qhb = (u16*)p; p += 1048576;  // 2048*1024 u16 = 4MB = 1,048,576 floats
  u16* qlb = (u16*)p; p += 1048576;
  u16* khb = (u16*)p; p += 1048576;
  u16* klb = (u16*)p; p += 1048576;
  u16* vhb = (u16*)p; p += 1048576;
  u16* vlb = (u16*)p; p += 1048576;
  u16* xnh  = (u16*)p; p += 524288;  // 2048*512 u16 = 2MB = 524,288 floats
  u16* upWt = (u16*)p; p += 524288;  // 2048*512 u16
  u16* dnWt = (u16*)p; p += 262144;  // 512*1024 u16 = 1MB = 262,144 floats
  u16* hsbh = (u16*)xm;              // 2048*1024 u16 aliases xm (8MB region)
  // total: 15,122,432 floats = 60.5 MB  (ws = 64 MiB)

  embed_kernel<<<2048, 128, 0, stream>>>(x_enc, x_mark, emb_W, emb_b, x);

  for (int L = 0; L < 4; L++) {
    ln_kernel<<<2048, 256, 0, stream>>>(x, ln_w + L * 512, xnh);
    transpose_bf16_kernel<<<dim3(8, 32), 256, 0, stream>>>(
        up_W + (size_t)L * 512 * 2048, upWt, 512, 2048);
    gemm_bf16<0><<<dim3(16, 16), 256, 0, stream>>>(
        xnh, upWt, xm, z, 2048, 2048, 512, 1024, 1024);
    conv_silu_kernel<<<2048, 256, 0, stream>>>(xm, conv_W + L * 4096, conv_b + L * 1024, xc);
    qkv_headwise_kernel<<<2048, 256, 0, stream>>>(
        xc, xm, q_W + L * 4096, k_W + L * 4096, v_W + L * 4096,
        qhb, qlb, khb, klb, vhb, vlb);
    gates_kernel<<<2048, 256, 0, stream>>>(
        qhb, qlb, khb, klb, vhb, vlb,
        ig_W + L * 24576, ig_b + L * 8, fg_W + L * 24576, fg_b + L * 8, igb_, fgb_);
    scan_kernel<<<16, 1024, 0, stream>>>(igb_, fgb_, ab, rmb, enmb);
    attn_mfma_kernel<<<dim3(16, 16), 256, 0, stream>>>(
        qhb, qlb, khb, klb, vhb, vlb, ab, rmb, enmb, xc, z,
        skip_w + L * 1024, onorm_w + L * 1024, hsbh);
    transpose_bf16_kernel<<<dim3(16, 8), 256, 0, stream>>>(
        down_W + (size_t)L * 1024 * 512, dnWt, 1024, 512);
    gemm_bf16<1><<<dim3(4, 16), 256, 0, stream>>>(
        hsbh, dnWt, x, nullptr, 2048, 512, 1024, 1 << 30, 512);
  }

  ln_final_kernel<<<192, 256, 0, stream>>>(x, post_ln, ln96);
  head_kernel<<<192, 64, 0, stream>>>(ln96, head_W, head_b, (float*)d_out);
}

// Round 10
// 743.275 us; speedup vs baseline: 2.5906x; 1.2682x over previous
//
#include <hip/hip_runtime.h>
#include <hip/hip_bf16.h>

#define S_LEN 1024
#define E_DIM 512
#define INNER_D 1024
#define NHEAD 8
#define DHEAD 128

typedef unsigned short u16;
typedef unsigned int u32;
typedef __attribute__((ext_vector_type(8))) short short8;
typedef __attribute__((ext_vector_type(4))) float f32x4;

union S8 { short8 v; u16 u[8]; uint4 q; };

__device__ __forceinline__ u16 f2bf(float f) {
  u32 u = __float_as_uint(f);
  u32 r = u + 0x7FFFu + ((u >> 16) & 1u);
  return (u16)(r >> 16);
}
__device__ __forceinline__ float bf2f(u16 u) { return __uint_as_float(((u32)u) << 16); }

// ---------------- embedding ----------------
__global__ __launch_bounds__(128) void embed_kernel(
    const float* __restrict__ xe, const float* __restrict__ xm,
    const float* __restrict__ W, const float* __restrict__ bias,
    float* __restrict__ x)
{
  int row = blockIdx.x;
  int tid = threadIdx.x;
  __shared__ float in_s[25];
  if (tid < 21) in_s[tid] = xe[row * 21 + tid];
  else if (tid < 25) in_s[tid] = xm[row * 4 + tid - 21];
  __syncthreads();
#pragma unroll
  for (int rep = 0; rep < 4; rep++) {
    int e = tid + rep * 128;
    float acc = bias[e];
#pragma unroll
    for (int i = 0; i < 25; i++) acc += in_s[i] * W[i * E_DIM + e];
    x[(size_t)row * E_DIM + e] = acc;
  }
}

// ---------------- layernorm -> bf16 ----------------
__global__ __launch_bounds__(256) void ln_kernel(
    const float* __restrict__ x, const float* __restrict__ w, u16* __restrict__ out)
{
  int row = blockIdx.x, tid = threadIdx.x;
  const float* xr = x + (size_t)row * E_DIM;
  float2 v = *(const float2*)(xr + tid * 2);
  float s = v.x + v.y, q = v.x * v.x + v.y * v.y;
#pragma unroll
  for (int off = 32; off; off >>= 1) { s += __shfl_xor(s, off); q += __shfl_xor(q, off); }
  __shared__ float ssum[4], ssq[4];
  int wv = tid >> 6;
  if ((tid & 63) == 0) { ssum[wv] = s; ssq[wv] = q; }
  __syncthreads();
  s = ssum[0] + ssum[1] + ssum[2] + ssum[3];
  q = ssq[0] + ssq[1] + ssq[2] + ssq[3];
  float mu = s * (1.f / E_DIM);
  float var = q * (1.f / E_DIM) - mu * mu;
  float rs = rsqrtf(var + 1e-5f);
  int e = tid * 2;
  ushort2 o;
  o.x = f2bf((v.x - mu) * rs * w[e]);
  o.y = f2bf((v.y - mu) * rs * w[e + 1]);
  *(ushort2*)(out + (size_t)row * E_DIM + e) = o;
}

__global__ __launch_bounds__(256) void ln_final_kernel(
    const float* __restrict__ x, const float* __restrict__ w, float* __restrict__ out)
{
  int ridx = blockIdx.x;
  int b = ridx / 96, r = ridx % 96;
  int row = b * S_LEN + (S_LEN - 96) + r;
  int tid = threadIdx.x;
  const float* xr = x + (size_t)row * E_DIM;
  float2 v = *(const float2*)(xr + tid * 2);
  float s = v.x + v.y, q = v.x * v.x + v.y * v.y;
#pragma unroll
  for (int off = 32; off; off >>= 1) { s += __shfl_xor(s, off); q += __shfl_xor(q, off); }
  __shared__ float ssum[4], ssq[4];
  int wv = tid >> 6;
  if ((tid & 63) == 0) { ssum[wv] = s; ssq[wv] = q; }
  __syncthreads();
  s = ssum[0] + ssum[1] + ssum[2] + ssum[3];
  q = ssq[0] + ssq[1] + ssq[2] + ssq[3];
  float mu = s * (1.f / E_DIM);
  float var = q * (1.f / E_DIM) - mu * mu;
  float rs = rsqrtf(var + 1e-5f);
  int e = tid * 2;
  float2 o;
  o.x = (v.x - mu) * rs * w[e];
  o.y = (v.y - mu) * rs * w[e + 1];
  *(float2*)(out + (size_t)ridx * E_DIM + e) = o;
}

// ---------------- transpose f32 [K][N] -> bf16 [N][K] ----------------
__global__ __launch_bounds__(256) void transpose_bf16_kernel(
    const float* __restrict__ in, u16* __restrict__ out, int K, int N)
{
  __shared__ u16 T[64][72];
  int k0 = blockIdx.x * 64, n0 = blockIdx.y * 64;
  int t = threadIdx.x;
  int kr = t >> 2, nseg = (t & 3) * 16;
  const float* src = in + (size_t)(k0 + kr) * N + n0 + nseg;
#pragma unroll
  for (int j = 0; j < 16; j++) T[kr][nseg + j] = f2bf(src[j]);
  __syncthreads();
  int nr = t >> 2, kseg = (t & 3) * 16;
  u32 u[8];
#pragma unroll
  for (int rr = 0; rr < 8; rr++) {
    u32 lo = T[kseg + 2 * rr][nr];
    u32 hi = T[kseg + 2 * rr + 1][nr];
    u[rr] = lo | (hi << 16);
  }
  u16* dst = out + (size_t)(n0 + nr) * K + k0 + kseg;
  uint4 w0 = {u[0], u[1], u[2], u[3]};
  uint4 w1 = {u[4], u[5], u[6], u[7]};
  *(uint4*)dst = w0;
  *(uint4*)(dst + 8) = w1;
}

// ---------------- bf16 MFMA GEMM 128x128: C[M,N] (+)= A[M,K] @ Bt[N,K]^T ----------------
template <int ADD>
__global__ __launch_bounds__(256) void gemm_bf16(
    const u16* __restrict__ A, const u16* __restrict__ Bt,
    float* __restrict__ C0, float* __restrict__ C1,
    int M, int N, int K, int split_col, int ldc)
{
  __shared__ u16 As[128][40];
  __shared__ u16 Bs[128][40];
  const int tid = threadIdx.x;
  const int row0 = blockIdx.y * 128, col0 = blockIdx.x * 128;
  const int wave = tid >> 6, lane = tid & 63;
  const int wr = wave >> 1, wc = wave & 1;
  const int lm = lane & 15, lq = lane >> 4;
  const int sr = tid >> 1, sp = (tid & 1) * 16;
  f32x4 acc[4][4] = {};
  for (int k0 = 0; k0 < K; k0 += 32) {
    __syncthreads();
    const uint4* sa = (const uint4*)(A + (size_t)(row0 + sr) * K + k0 + sp);
    *(uint4*)&As[sr][sp] = sa[0];
    *(uint4*)&As[sr][sp + 8] = sa[1];
    const uint4* sb = (const uint4*)(Bt + (size_t)(col0 + sr) * K + k0 + sp);
    *(uint4*)&Bs[sr][sp] = sb[0];
    *(uint4*)&Bs[sr][sp + 8] = sb[1];
    __syncthreads();
    short8 af[4], bf[4];
#pragma unroll
    for (int i = 0; i < 4; i++) af[i] = *(const short8*)&As[wr * 64 + i * 16 + lm][lq * 8];
#pragma unroll
    for (int j = 0; j < 4; j++) bf[j] = *(const short8*)&Bs[wc * 64 + j * 16 + lm][lq * 8];
#pragma unroll
    for (int i = 0; i < 4; i++)
#pragma unroll
      for (int j = 0; j < 4; j++)
        acc[i][j] = __builtin_amdgcn_mfma_f32_16x16x32_bf16(af[i], bf[j], acc[i][j], 0, 0, 0);
  }
  float* Cb = C0;
  int cadj = 0;
  if (C1 && col0 >= split_col) { Cb = C1; cadj = split_col; }
#pragma unroll
  for (int i = 0; i < 4; i++) {
#pragma unroll
    for (int j = 0; j < 4; j++) {
      int col = col0 - cadj + wc * 64 + j * 16 + lm;
#pragma unroll
      for (int r = 0; r < 4; r++) {
        int row = row0 + wr * 64 + i * 16 + lq * 4 + r;
        float* cp = Cb + (size_t)row * ldc + col;
        if (ADD) *cp += acc[i][j][r];
        else *cp = acc[i][j][r];
      }
    }
  }
}

// ---------------- bf16 MFMA GEMM 64x64 (for the narrow down-proj; 256 blocks) ----------------
template <int ADD>
__global__ __launch_bounds__(256) void gemm_bf16_64(
    const u16* __restrict__ A, const u16* __restrict__ Bt,
    float* __restrict__ C, int M, int N, int K, int ldc)
{
  __shared__ u16 As[64][40];
  __shared__ u16 Bs[64][40];
  const int tid = threadIdx.x;
  const int row0 = blockIdx.y * 64, col0 = blockIdx.x * 64;
  const int wave = tid >> 6, lane = tid & 63;
  const int wr = wave >> 1, wc = wave & 1;
  const int lm = lane & 15, lq = lane >> 4;
  const int sr = tid >> 2, sp = (tid & 3) * 8;
  f32x4 acc[2][2] = {};
  for (int k0 = 0; k0 < K; k0 += 32) {
    __syncthreads();
    *(uint4*)&As[sr][sp] = *(const uint4*)(A + (size_t)(row0 + sr) * K + k0 + sp);
    *(uint4*)&Bs[sr][sp] = *(const uint4*)(Bt + (size_t)(col0 + sr) * K + k0 + sp);
    __syncthreads();
    short8 af[2], bf[2];
#pragma unroll
    for (int i = 0; i < 2; i++) af[i] = *(const short8*)&As[wr * 32 + i * 16 + lm][lq * 8];
#pragma unroll
    for (int j = 0; j < 2; j++) bf[j] = *(const short8*)&Bs[wc * 32 + j * 16 + lm][lq * 8];
#pragma unroll
    for (int i = 0; i < 2; i++)
#pragma unroll
      for (int j = 0; j < 2; j++)
        acc[i][j] = __builtin_amdgcn_mfma_f32_16x16x32_bf16(af[i], bf[j], acc[i][j], 0, 0, 0);
  }
#pragma unroll
  for (int i = 0; i < 2; i++) {
#pragma unroll
    for (int j = 0; j < 2; j++) {
      int col = col0 + wc * 32 + j * 16 + lm;
#pragma unroll
      for (int r = 0; r < 4; r++) {
        int row = row0 + wr * 32 + i * 16 + lq * 4 + r;
        float* cp = C + (size_t)row * ldc + col;
        if (ADD) *cp += acc[i][j][r];
        else *cp = acc[i][j][r];
      }
    }
  }
}

// ---------------- causal depthwise conv (K=4) + bias + SiLU ----------------
__global__ __launch_bounds__(256) void conv_silu_kernel(
    const float* __restrict__ xm, const float* __restrict__ cw, const float* __restrict__ cb,
    float* __restrict__ xc)
{
  int idx = blockIdx.x * 256 + threadIdx.x;
  int g = idx & 255;
  int row = idx >> 8;
  int s = row & (S_LEN - 1);
  int c0 = g * 4;
  const float* base = xm + (size_t)row * INNER_D + c0;
  float4 acc = {0.f, 0.f, 0.f, 0.f};
#pragma unroll
  for (int kk = 0; kk < 4; kk++) {
    int ts = s - 3 + kk;
    if (ts >= 0) {
      float4 xv = *(const float4*)(base + (ptrdiff_t)(kk - 3) * INNER_D);
      acc.x += xv.x * cw[(c0 + 0) * 4 + kk];
      acc.y += xv.y * cw[(c0 + 1) * 4 + kk];
      acc.z += xv.z * cw[(c0 + 2) * 4 + kk];
      acc.w += xv.w * cw[(c0 + 3) * 4 + kk];
    }
  }
  acc.x += cb[c0 + 0]; acc.y += cb[c0 + 1];
  acc.z += cb[c0 + 2]; acc.w += cb[c0 + 3];
  acc.x = acc.x / (1.f + __expf(-acc.x));
  acc.y = acc.y / (1.f + __expf(-acc.y));
  acc.z = acc.z / (1.f + __expf(-acc.z));
  acc.w = acc.w / (1.f + __expf(-acc.w));
  *(float4*)(xc + (size_t)row * INNER_D + c0) = acc;
}

// ---------------- headwise 4x4 projections -> bf16 q,k,v ----------------
__global__ __launch_bounds__(256) void qkv_headwise_kernel(
    const float* __restrict__ xc, const float* __restrict__ xm,
    const float* __restrict__ qw, const float* __restrict__ kw, const float* __restrict__ vw,
    u16* __restrict__ q, u16* __restrict__ k, u16* __restrict__ v)
{
  int idx = blockIdx.x * 256 + threadIdx.x;
  int g = idx & 255;
  size_t row = idx >> 8;
  float4 xc4 = *(const float4*)(xc + row * INNER_D + g * 4);
  float4 xm4 = *(const float4*)(xm + row * INNER_D + g * 4);
  const float* qg = qw + g * 16;
  const float* kg = kw + g * 16;
  const float* vg = vw + g * 16;
  float xcv[4] = {xc4.x, xc4.y, xc4.z, xc4.w};
  float xmv[4] = {xm4.x, xm4.y, xm4.z, xm4.w};
  ushort4 qs, ks, vs;
  u16* qp = (u16*)&qs; u16* kp = (u16*)&ks; u16* vp = (u16*)&vs;
#pragma unroll
  for (int o = 0; o < 4; o++) {
    float aq = 0.f, ak = 0.f, av = 0.f;
#pragma unroll
    for (int d = 0; d < 4; d++) {
      aq += xcv[d] * qg[o * 4 + d];
      ak += xcv[d] * kg[o * 4 + d];
      av += xmv[d] * vg[o * 4 + d];
    }
    qp[o] = f2bf(aq); kp[o] = f2bf(ak); vp[o] = f2bf(av);
  }
  size_t off = row * INNER_D + g * 4;
  *(ushort4*)(q + off) = qs;
  *(ushort4*)(k + off) = ks;
  *(ushort4*)(v + off) = vs;
}

// ---------------- gate GEMVs (bf16 inputs) ----------------
__global__ __launch_bounds__(256) void gates_kernel(
    const u16* __restrict__ q, const u16* __restrict__ k, const u16* __restrict__ v,
    const float* __restrict__ igW, const float* __restrict__ igb,
    const float* __restrict__ fgW, const float* __restrict__ fgb,
    float* __restrict__ ig, float* __restrict__ fg)
{
  int row = blockIdx.x;
  int b = row >> 10, s = row & (S_LEN - 1);
  int tid = threadIdx.x;
  float ia[8] = {}, fa[8] = {};
#pragma unroll
  for (int i = 0; i < 12; i++) {
    int j = tid + i * 256;
    float xv;
    if (j < 1024) xv = bf2f(q[(size_t)row * INNER_D + j]);
    else if (j < 2048) xv = bf2f(k[(size_t)row * INNER_D + j - 1024]);
    else xv = bf2f(v[(size_t)row * INNER_D + j - 2048]);
    float4 wi0 = *(const float4*)(igW + (size_t)j * 8);
    float4 wi1 = *(const float4*)(igW + (size_t)j * 8 + 4);
    float4 wf0 = *(const float4*)(fgW + (size_t)j * 8);
    float4 wf1 = *(const float4*)(fgW + (size_t)j * 8 + 4);
    ia[0] += xv * wi0.x; ia[1] += xv * wi0.y; ia[2] += xv * wi0.z; ia[3] += xv * wi0.w;
    ia[4] += xv * wi1.x; ia[5] += xv * wi1.y; ia[6] += xv * wi1.z; ia[7] += xv * wi1.w;
    fa[0] += xv * wf0.x; fa[1] += xv * wf0.y; fa[2] += xv * wf0.z; fa[3] += xv * wf0.w;
    fa[4] += xv * wf1.x; fa[5] += xv * wf1.y; fa[6] += xv * wf1.z; fa[7] += xv * wf1.w;
  }
#pragma unroll
  for (int off = 32; off; off >>= 1) {
#pragma unroll
    for (int n = 0; n < 8; n++) {
      ia[n] += __shfl_xor(ia[n], off);
      fa[n] += __shfl_xor(fa[n], off);
    }
  }
  __shared__ float red[2][4][8];
  int wv = tid >> 6;
  if ((tid & 63) == 0) {
#pragma unroll
    for (int n = 0; n < 8; n++) { red[0][wv][n] = ia[n]; red[1][wv][n] = fa[n]; }
  }
  __syncthreads();
  if (tid < 8) {
    float si = red[0][0][tid] + red[0][1][tid] + red[0][2][tid] + red[0][3][tid];
    float sf = red[1][0][tid] + red[1][1][tid] + red[1][2][tid] + red[1][3][tid];
    size_t o = ((size_t)(b * NHEAD + tid) << 10) + s;
    ig[o] = si + igb[tid];
    fg[o] = sf + fgb[tid];
  }
}

// ---------------- per-(b,h) scans ----------------
__global__ __launch_bounds__(1024) void scan_kernel(
    const float* __restrict__ ig, const float* __restrict__ fg,
    float* __restrict__ a, float* __restrict__ rm, float* __restrict__ enm)
{
  int bh = blockIdx.x;
  int t = threadIdx.x;
  __shared__ float buf[1024];
  size_t o = ((size_t)bh << 10) + t;
  float f = fg[o];
  float lf = (f >= 0.f) ? -log1pf(__expf(-f)) : f - log1pf(__expf(f));
  buf[t] = lf;
  __syncthreads();
  float run = lf;
  for (int off = 1; off < 1024; off <<= 1) {
    float add = (t >= off) ? buf[t - off] : 0.f;
    __syncthreads();
    run += add;
    buf[t] = run;
    __syncthreads();
  }
  float cs = run;
  float av = ig[o] - cs;
  a[o] = av;
  buf[t] = av;
  __syncthreads();
  float rmx = av;
  for (int off = 1; off < 1024; off <<= 1) {
    float m = (t >= off) ? buf[t - off] : -3.4e38f;
    __syncthreads();
    rmx = fmaxf(rmx, m);
    buf[t] = rmx;
    __syncthreads();
  }
  rm[o] = rmx;
  enm[o] = __expf(-(cs + rmx));
}

// ---------------- MFMA attention, plain bf16, XCD-swizzled grid ----------------
// blockIdx.x = bh (linear id mod 8 = bh mod 8 -> same-bh blocks share an XCD; K/V L2-resident)
// blockIdx.y = qt
__global__ __launch_bounds__(256) void attn_mfma_kernel(
    const u16* __restrict__ qhg, const u16* __restrict__ khg, const u16* __restrict__ vhg,
    const float* __restrict__ a_arr, const float* __restrict__ rm_arr, const float* __restrict__ enm_arr,
    const float* __restrict__ xc, const float* __restrict__ z,
    const float* __restrict__ skip, const float* __restrict__ onw,
    u16* __restrict__ hs)
{
  const int bh = blockIdx.x;    // 0..15
  const int qt = blockIdx.y;    // 0..15
  const int b = bh >> 3, h = bh & 7;
  const int s0 = qt * 64;
  const int tid = threadIdx.x;
  const int wave = tid >> 6, lane = tid & 63;
  const int lm = lane & 15, lq = lane >> 4;
  const size_t rowbase = (size_t)b * S_LEN;
  const int c0 = h * DHEAD;

  __shared__ u16 Qs[64 * 136];   // [s][d]
  __shared__ u16 Ks[64 * 136];   // [t][d]
  __shared__ u16 Vt[128 * 72];   // [d][t], 144B rows (16B aligned)
  __shared__ u16 Ws[64 * 72];    // [s][t] wave-private bands
  __shared__ float as_[64];

  // stage Q
#pragma unroll
  for (int rep = 0; rep < 4; rep++) {
    int idx = rep * 256 + tid;
    int r = idx >> 4, seg = (idx & 15) * 8;
    *(uint4*)&Qs[r * 136 + seg] =
        *(const uint4*)(qhg + (rowbase + s0 + r) * INNER_D + c0 + seg);
  }
  float rmv[4];
#pragma unroll
  for (int r = 0; r < 4; r++)
    rmv[r] = rm_arr[(size_t)bh * S_LEN + s0 + wave * 16 + lq * 4 + r];

  f32x4 accH[8] = {};
  float sc_acc[4] = {0.f, 0.f, 0.f, 0.f};
  const float scale = 0.08838834764831845f;  // 1/sqrt(128)

  for (int kt = 0; kt <= qt; kt++) {
    const int t0 = kt * 64;
    __syncthreads();
    // stage K [t][d]
#pragma unroll
    for (int rep = 0; rep < 4; rep++) {
      int idx = rep * 256 + tid;
      int r = idx >> 4, seg = (idx & 15) * 8;
      *(uint4*)&Ks[r * 136 + seg] =
          *(const uint4*)(khg + (rowbase + t0 + r) * INNER_D + c0 + seg);
    }
    // stage V transposed, conflict-free: lane owns (t = tid&63), 8 consecutive d
#pragma unroll
    for (int rep = 0; rep < 4; rep++) {
      int idx = rep * 256 + tid;
      int t = idx & 63, dgrp = idx >> 6;  // 0..15
      S8 vv;
      vv.q = *(const uint4*)(vhg + (rowbase + t0 + t) * INNER_D + c0 + dgrp * 8);
#pragma unroll
      for (int j = 0; j < 8; j++) Vt[(dgrp * 8 + j) * 72 + t] = vv.u[j];
    }
    if (tid < 64) as_[tid] = a_arr[(size_t)bh * S_LEN + t0 + tid];
    __syncthreads();

    // phase A: P[16 band][64] per wave
    f32x4 pacc[4] = {};
#pragma unroll
    for (int kc = 0; kc < 4; kc++) {
      short8 aq = *(const short8*)&Qs[(wave * 16 + lm) * 136 + kc * 32 + lq * 8];
#pragma unroll
      for (int cb = 0; cb < 4; cb++) {
        short8 bk = *(const short8*)&Ks[(cb * 16 + lm) * 136 + kc * 32 + lq * 8];
        pacc[cb] = __builtin_amdgcn_mfma_f32_16x16x32_bf16(aq, bk, pacc[cb], 0, 0, 0);
      }
    }

    // w + causal mask; bf16 into wave-private Ws band; fp32 rowsum
    float wpart[4] = {0.f, 0.f, 0.f, 0.f};
#pragma unroll
    for (int cb = 0; cb < 4; cb++) {
      int colg = t0 + cb * 16 + lm;
      float ea = as_[cb * 16 + lm];
#pragma unroll
      for (int r = 0; r < 4; r++) {
        int rowg = s0 + wave * 16 + lq * 4 + r;
        float wv = pacc[cb][r] * scale * __expf(ea - rmv[r]);
        if (colg > rowg) wv = 0.f;
        wpart[r] += wv;
        Ws[(wave * 16 + lq * 4 + r) * 72 + cb * 16 + lm] = f2bf(wv);
      }
    }
#pragma unroll
    for (int r = 0; r < 4; r++) {
      float sr = wpart[r];
      sr += __shfl_xor(sr, 1); sr += __shfl_xor(sr, 2);
      sr += __shfl_xor(sr, 4); sr += __shfl_xor(sr, 8);
      sc_acc[r] += sr;
    }

    // phase B: H[16 band][128] += w[16][64] @ V[64][128]
#pragma unroll
    for (int kc = 0; kc < 2; kc++) {
      short8 aw = *(const short8*)&Ws[(wave * 16 + lm) * 72 + kc * 32 + lq * 8];
#pragma unroll
      for (int nb = 0; nb < 8; nb++) {
        short8 bv = *(const short8*)&Vt[(nb * 16 + lm) * 72 + kc * 32 + lq * 8];
        accH[nb] = __builtin_amdgcn_mfma_f32_16x16x32_bf16(aw, bv, accH[nb], 0, 0, 0);
      }
    }
  }

  // norm + headwise LN (register/shuffle only)
  float inv[4], muv[4], rsv[4];
#pragma unroll
  for (int r = 0; r < 4; r++) {
    int rowg = s0 + wave * 16 + lq * 4 + r;
    float nrm = fmaxf(fabsf(sc_acc[r]), enm_arr[(size_t)bh * S_LEN + rowg]);
    inv[r] = 1.f / (nrm + 1e-6f);
  }
#pragma unroll
  for (int r = 0; r < 4; r++) {
    float s = 0.f, qq = 0.f;
#pragma unroll
    for (int nb = 0; nb < 8; nb++) {
      float hv = accH[nb][r] * inv[r];
      accH[nb][r] = hv;
      s += hv; qq += hv * hv;
    }
    s += __shfl_xor(s, 1); s += __shfl_xor(s, 2); s += __shfl_xor(s, 4); s += __shfl_xor(s, 8);
    qq += __shfl_xor(qq, 1); qq += __shfl_xor(qq, 2); qq += __shfl_xor(qq, 4); qq += __shfl_xor(qq, 8);
    float mu = s * (1.f / DHEAD);
    float var = qq * (1.f / DHEAD) - mu * mu;
    muv[r] = mu;
    rsv[r] = rsqrtf(var + 1e-5f);
  }

  // epilogue
  float ow[8], sk[8];
#pragma unroll
  for (int nb = 0; nb < 8; nb++) {
    ow[nb] = onw[c0 + nb * 16 + lm];
    sk[nb] = skip[c0 + nb * 16 + lm];
  }
#pragma unroll
  for (int r = 0; r < 4; r++) {
    int rowg = s0 + wave * 16 + lq * 4 + r;
    size_t base = (rowbase + rowg) * INNER_D + c0;
#pragma unroll
    for (int nb = 0; nb < 8; nb++) {
      int d = nb * 16 + lm;
      float xcv = xc[base + d];
      float zv = z[base + d];
      float hn = (accH[nb][r] - muv[r]) * rsv[r] * ow[nb] + sk[nb] * xcv;
      float o = hn * (zv / (1.f + __expf(-zv)));
      hs[base + d] = f2bf(o);
    }
  }
}

// ---------------- head ----------------
__global__ __launch_bounds__(64) void head_kernel(
    const float* __restrict__ ln96, const float* __restrict__ hW, const float* __restrict__ hb,
    float* __restrict__ out)
{
  int row = blockIdx.x;
  int n = threadIdx.x;
  if (n >= 21) return;
  float acc = hb[n];
  const float* xr = ln96 + (size_t)row * E_DIM;
  for (int kk = 0; kk < E_DIM; kk++) acc += xr[kk] * hW[kk * 21 + n];
  out[row * 21 + n] = acc;
}

extern "C" void kernel_launch(void* const* d_in, const int* in_sizes, int n_in,
                              void* d_out, int out_size, void* d_ws, size_t ws_size,
                              hipStream_t stream)
{
  const float* x_enc   = (const float*)d_in[0];
  const float* x_mark  = (const float*)d_in[1];
  const float* emb_W   = (const float*)d_in[4];
  const float* emb_b   = (const float*)d_in[5];
  const float* ln_w    = (const float*)d_in[6];
  const float* up_W    = (const float*)d_in[7];
  const float* conv_W  = (const float*)d_in[8];
  const float* conv_b  = (const float*)d_in[9];
  const float* q_W     = (const float*)d_in[10];
  const float* k_W     = (const float*)d_in[11];
  const float* v_W     = (const float*)d_in[12];
  const float* ig_W    = (const float*)d_in[13];
  const float* ig_b    = (const float*)d_in[14];
  const float* fg_W    = (const float*)d_in[15];
  const float* fg_b    = (const float*)d_in[16];
  const float* skip_w  = (const float*)d_in[17];
  const float* onorm_w = (const float*)d_in[18];
  const float* down_W  = (const float*)d_in[19];
  const float* post_ln = (const float*)d_in[20];
  const float* head_W  = (const float*)d_in[21];
  const float* head_b  = (const float*)d_in[22];

  float* p = (float*)d_ws;
  float* x    = p; p += 1048576;   // 2048*512 f32
  float* xm   = p; p += 2097152;   // 2048*1024 f32; reused as hsbh (bf16) after qkv
  float* z    = p; p += 2097152;
  float* xc   = p; p += 2097152;
  float* igb_ = p; p += 16384;
  float* fgb_ = p; p += 16384;
  float* ab   = p; p += 16384;
  float* rmb  = p; p += 16384;
  float* enmb = p; p += 16384;
  float* ln96 = p; p += 98304;
  u16* qhb = (u16*)p; p += 1048576;  // 2048*1024 u16 = 4MB
  u16* khb = (u16*)p; p += 1048576;
  u16* vhb = (u16*)p; p += 1048576;
  u16* xnh  = (u16*)p; p += 524288;  // 2048*512 u16 = 2MB
  u16* upWt = (u16*)p; p += 524288;  // 2048*512 u16
  u16* dnWt = (u16*)p; p += 262144;  // 512*1024 u16 = 1MB
  u16* hsbh = (u16*)xm;              // 2048*1024 u16 aliases xm
  // total ~12.0M floats = 48 MB (ws = 64 MiB)

  embed_kernel<<<2048, 128, 0, stream>>>(x_enc, x_mark, emb_W, emb_b, x);

  for (int L = 0; L < 4; L++) {
    ln_kernel<<<2048, 256, 0, stream>>>(x, ln_w + L * 512, xnh);
    transpose_bf16_kernel<<<dim3(8, 32), 256, 0, stream>>>(
        up_W + (size_t)L * 512 * 2048, upWt, 512, 2048);
    gemm_bf16<0><<<dim3(16, 16), 256, 0, stream>>>(
        xnh, upWt, xm, z, 2048, 2048, 512, 1024, 1024);
    conv_silu_kernel<<<2048, 256, 0, stream>>>(xm, conv_W + L * 4096, conv_b + L * 1024, xc);
    qkv_headwise_kernel<<<2048, 256, 0, stream>>>(
        xc, xm, q_W + L * 4096, k_W + L * 4096, v_W + L * 4096, qhb, khb, vhb);
    gates_kernel<<<2048, 256, 0, stream>>>(
        qhb, khb, vhb,
        ig_W + L * 24576, ig_b + L * 8, fg_W + L * 24576, fg_b + L * 8, igb_, fgb_);
    scan_kernel<<<16, 1024, 0, stream>>>(igb_, fgb_, ab, rmb, enmb);
    attn_mfma_kernel<<<dim3(16, 16), 256, 0, stream>>>(
        qhb, khb, vhb, ab, rmb, enmb, xc, z,
        skip_w + L * 1024, onorm_w + L * 1024, hsbh);
    transpose_bf16_kernel<<<dim3(16, 8), 256, 0, stream>>>(
        down_W + (size_t)L * 1024 * 512, dnWt, 1024, 512);
    gemm_bf16_64<1><<<dim3(8, 32), 256, 0, stream>>>(
        hsbh, dnWt, x, 2048, 512, 1024, 512);
  }

  ln_final_kernel<<<192, 256, 0, stream>>>(x, post_ln, ln96);
  head_kernel<<<192, 64, 0, stream>>>(ln96, head_W, head_b, (float*)d_out);
}

// Round 11
// 701.402 us; speedup vs baseline: 2.7453x; 1.0597x over previous
//
#include <hip/hip_runtime.h>
#include <hip/hip_bf16.h>

#define S_LEN 1024
#define E_DIM 512
#define INNER_D 1024
#define NHEAD 8
#define DHEAD 128

typedef unsigned short u16;
typedef unsigned int u32;
typedef __attribute__((ext_vector_type(8))) short short8;
typedef __attribute__((ext_vector_type(4))) float f32x4;

union S8 { short8 v; u16 u[8]; uint4 q; };

__device__ __forceinline__ u16 f2bf(float f) {
  u32 u = __float_as_uint(f);
  u32 r = u + 0x7FFFu + ((u >> 16) & 1u);
  return (u16)(r >> 16);
}
__device__ __forceinline__ float bf2f(u16 u) { return __uint_as_float(((u32)u) << 16); }

// ---------------- embedding ----------------
__global__ __launch_bounds__(128) void embed_kernel(
    const float* __restrict__ xe, const float* __restrict__ xm,
    const float* __restrict__ W, const float* __restrict__ bias,
    float* __restrict__ x)
{
  int row = blockIdx.x;
  int tid = threadIdx.x;
  __shared__ float in_s[25];
  if (tid < 21) in_s[tid] = xe[row * 21 + tid];
  else if (tid < 25) in_s[tid] = xm[row * 4 + tid - 21];
  __syncthreads();
#pragma unroll
  for (int rep = 0; rep < 4; rep++) {
    int e = tid + rep * 128;
    float acc = bias[e];
#pragma unroll
    for (int i = 0; i < 25; i++) acc += in_s[i] * W[i * E_DIM + e];
    x[(size_t)row * E_DIM + e] = acc;
  }
}

// ---------------- layernorm -> bf16 ----------------
__global__ __launch_bounds__(256) void ln_kernel(
    const float* __restrict__ x, const float* __restrict__ w, u16* __restrict__ out)
{
  int row = blockIdx.x, tid = threadIdx.x;
  const float* xr = x + (size_t)row * E_DIM;
  float2 v = *(const float2*)(xr + tid * 2);
  float s = v.x + v.y, q = v.x * v.x + v.y * v.y;
#pragma unroll
  for (int off = 32; off; off >>= 1) { s += __shfl_xor(s, off); q += __shfl_xor(q, off); }
  __shared__ float ssum[4], ssq[4];
  int wv = tid >> 6;
  if ((tid & 63) == 0) { ssum[wv] = s; ssq[wv] = q; }
  __syncthreads();
  s = ssum[0] + ssum[1] + ssum[2] + ssum[3];
  q = ssq[0] + ssq[1] + ssq[2] + ssq[3];
  float mu = s * (1.f / E_DIM);
  float var = q * (1.f / E_DIM) - mu * mu;
  float rs = rsqrtf(var + 1e-5f);
  int e = tid * 2;
  ushort2 o;
  o.x = f2bf((v.x - mu) * rs * w[e]);
  o.y = f2bf((v.y - mu) * rs * w[e + 1]);
  *(ushort2*)(out + (size_t)row * E_DIM + e) = o;
}

__global__ __launch_bounds__(256) void ln_final_kernel(
    const float* __restrict__ x, const float* __restrict__ w, float* __restrict__ out)
{
  int ridx = blockIdx.x;
  int b = ridx / 96, r = ridx % 96;
  int row = b * S_LEN + (S_LEN - 96) + r;
  int tid = threadIdx.x;
  const float* xr = x + (size_t)row * E_DIM;
  float2 v = *(const float2*)(xr + tid * 2);
  float s = v.x + v.y, q = v.x * v.x + v.y * v.y;
#pragma unroll
  for (int off = 32; off; off >>= 1) { s += __shfl_xor(s, off); q += __shfl_xor(q, off); }
  __shared__ float ssum[4], ssq[4];
  int wv = tid >> 6;
  if ((tid & 63) == 0) { ssum[wv] = s; ssq[wv] = q; }
  __syncthreads();
  s = ssum[0] + ssum[1] + ssum[2] + ssum[3];
  q = ssq[0] + ssq[1] + ssq[2] + ssq[3];
  float mu = s * (1.f / E_DIM);
  float var = q * (1.f / E_DIM) - mu * mu;
  float rs = rsqrtf(var + 1e-5f);
  int e = tid * 2;
  float2 o;
  o.x = (v.x - mu) * rs * w[e];
  o.y = (v.y - mu) * rs * w[e + 1];
  *(float2*)(out + (size_t)ridx * E_DIM + e) = o;
}

// ---------------- transpose f32 [K][N] -> bf16 [N][K] ----------------
__global__ __launch_bounds__(256) void transpose_bf16_kernel(
    const float* __restrict__ in, u16* __restrict__ out, int K, int N)
{
  __shared__ u16 T[64][72];
  int k0 = blockIdx.x * 64, n0 = blockIdx.y * 64;
  int t = threadIdx.x;
  int kr = t >> 2, nseg = (t & 3) * 16;
  const float* src = in + (size_t)(k0 + kr) * N + n0 + nseg;
#pragma unroll
  for (int j = 0; j < 16; j++) T[kr][nseg + j] = f2bf(src[j]);
  __syncthreads();
  int nr = t >> 2, kseg = (t & 3) * 16;
  u32 u[8];
#pragma unroll
  for (int rr = 0; rr < 8; rr++) {
    u32 lo = T[kseg + 2 * rr][nr];
    u32 hi = T[kseg + 2 * rr + 1][nr];
    u[rr] = lo | (hi << 16);
  }
  u16* dst = out + (size_t)(n0 + nr) * K + k0 + kseg;
  uint4 w0 = {u[0], u[1], u[2], u[3]};
  uint4 w1 = {u[4], u[5], u[6], u[7]};
  *(uint4*)dst = w0;
  *(uint4*)(dst + 8) = w1;
}

// ---------------- bf16 MFMA GEMM 128x128 ----------------
template <int ADD>
__global__ __launch_bounds__(256) void gemm_bf16(
    const u16* __restrict__ A, const u16* __restrict__ Bt,
    float* __restrict__ C0, float* __restrict__ C1,
    int M, int N, int K, int split_col, int ldc)
{
  __shared__ u16 As[128][40];
  __shared__ u16 Bs[128][40];
  const int tid = threadIdx.x;
  const int row0 = blockIdx.y * 128, col0 = blockIdx.x * 128;
  const int wave = tid >> 6, lane = tid & 63;
  const int wr = wave >> 1, wc = wave & 1;
  const int lm = lane & 15, lq = lane >> 4;
  const int sr = tid >> 1, sp = (tid & 1) * 16;
  f32x4 acc[4][4] = {};
  for (int k0 = 0; k0 < K; k0 += 32) {
    __syncthreads();
    const uint4* sa = (const uint4*)(A + (size_t)(row0 + sr) * K + k0 + sp);
    *(uint4*)&As[sr][sp] = sa[0];
    *(uint4*)&As[sr][sp + 8] = sa[1];
    const uint4* sb = (const uint4*)(Bt + (size_t)(col0 + sr) * K + k0 + sp);
    *(uint4*)&Bs[sr][sp] = sb[0];
    *(uint4*)&Bs[sr][sp + 8] = sb[1];
    __syncthreads();
    short8 af[4], bf[4];
#pragma unroll
    for (int i = 0; i < 4; i++) af[i] = *(const short8*)&As[wr * 64 + i * 16 + lm][lq * 8];
#pragma unroll
    for (int j = 0; j < 4; j++) bf[j] = *(const short8*)&Bs[wc * 64 + j * 16 + lm][lq * 8];
#pragma unroll
    for (int i = 0; i < 4; i++)
#pragma unroll
      for (int j = 0; j < 4; j++)
        acc[i][j] = __builtin_amdgcn_mfma_f32_16x16x32_bf16(af[i], bf[j], acc[i][j], 0, 0, 0);
  }
  float* Cb = C0;
  int cadj = 0;
  if (C1 && col0 >= split_col) { Cb = C1; cadj = split_col; }
#pragma unroll
  for (int i = 0; i < 4; i++) {
#pragma unroll
    for (int j = 0; j < 4; j++) {
      int col = col0 - cadj + wc * 64 + j * 16 + lm;
#pragma unroll
      for (int r = 0; r < 4; r++) {
        int row = row0 + wr * 64 + i * 16 + lq * 4 + r;
        float* cp = Cb + (size_t)row * ldc + col;
        if (ADD) *cp += acc[i][j][r];
        else *cp = acc[i][j][r];
      }
    }
  }
}

// ---------------- bf16 MFMA GEMM 64x64 ----------------
template <int ADD>
__global__ __launch_bounds__(256) void gemm_bf16_64(
    const u16* __restrict__ A, const u16* __restrict__ Bt,
    float* __restrict__ C, int M, int N, int K, int ldc)
{
  __shared__ u16 As[64][40];
  __shared__ u16 Bs[64][40];
  const int tid = threadIdx.x;
  const int row0 = blockIdx.y * 64, col0 = blockIdx.x * 64;
  const int wave = tid >> 6, lane = tid & 63;
  const int wr = wave >> 1, wc = wave & 1;
  const int lm = lane & 15, lq = lane >> 4;
  const int sr = tid >> 2, sp = (tid & 3) * 8;
  f32x4 acc[2][2] = {};
  for (int k0 = 0; k0 < K; k0 += 32) {
    __syncthreads();
    *(uint4*)&As[sr][sp] = *(const uint4*)(A + (size_t)(row0 + sr) * K + k0 + sp);
    *(uint4*)&Bs[sr][sp] = *(const uint4*)(Bt + (size_t)(col0 + sr) * K + k0 + sp);
    __syncthreads();
    short8 af[2], bf[2];
#pragma unroll
    for (int i = 0; i < 2; i++) af[i] = *(const short8*)&As[wr * 32 + i * 16 + lm][lq * 8];
#pragma unroll
    for (int j = 0; j < 2; j++) bf[j] = *(const short8*)&Bs[wc * 32 + j * 16 + lm][lq * 8];
#pragma unroll
    for (int i = 0; i < 2; i++)
#pragma unroll
      for (int j = 0; j < 2; j++)
        acc[i][j] = __builtin_amdgcn_mfma_f32_16x16x32_bf16(af[i], bf[j], acc[i][j], 0, 0, 0);
  }
#pragma unroll
  for (int i = 0; i < 2; i++) {
#pragma unroll
    for (int j = 0; j < 2; j++) {
      int col = col0 + wc * 32 + j * 16 + lm;
#pragma unroll
      for (int r = 0; r < 4; r++) {
        int row = row0 + wr * 32 + i * 16 + lq * 4 + r;
        float* cp = C + (size_t)row * ldc + col;
        if (ADD) *cp += acc[i][j][r];
        else *cp = acc[i][j][r];
      }
    }
  }
}

// ---------------- causal depthwise conv (K=4) + bias + SiLU ----------------
__global__ __launch_bounds__(256) void conv_silu_kernel(
    const float* __restrict__ xm, const float* __restrict__ cw, const float* __restrict__ cb,
    float* __restrict__ xc)
{
  int idx = blockIdx.x * 256 + threadIdx.x;
  int g = idx & 255;
  int row = idx >> 8;
  int s = row & (S_LEN - 1);
  int c0 = g * 4;
  const float* base = xm + (size_t)row * INNER_D + c0;
  float4 acc = {0.f, 0.f, 0.f, 0.f};
#pragma unroll
  for (int kk = 0; kk < 4; kk++) {
    int ts = s - 3 + kk;
    if (ts >= 0) {
      float4 xv = *(const float4*)(base + (ptrdiff_t)(kk - 3) * INNER_D);
      acc.x += xv.x * cw[(c0 + 0) * 4 + kk];
      acc.y += xv.y * cw[(c0 + 1) * 4 + kk];
      acc.z += xv.z * cw[(c0 + 2) * 4 + kk];
      acc.w += xv.w * cw[(c0 + 3) * 4 + kk];
    }
  }
  acc.x += cb[c0 + 0]; acc.y += cb[c0 + 1];
  acc.z += cb[c0 + 2]; acc.w += cb[c0 + 3];
  acc.x = acc.x / (1.f + __expf(-acc.x));
  acc.y = acc.y / (1.f + __expf(-acc.y));
  acc.z = acc.z / (1.f + __expf(-acc.z));
  acc.w = acc.w / (1.f + __expf(-acc.w));
  *(float4*)(xc + (size_t)row * INNER_D + c0) = acc;
}

// ---------------- headwise 4x4 projections -> bf16 q,k,v ----------------
__global__ __launch_bounds__(256) void qkv_headwise_kernel(
    const float* __restrict__ xc, const float* __restrict__ xm,
    const float* __restrict__ qw, const float* __restrict__ kw, const float* __restrict__ vw,
    u16* __restrict__ q, u16* __restrict__ k, u16* __restrict__ v)
{
  int idx = blockIdx.x * 256 + threadIdx.x;
  int g = idx & 255;
  size_t row = idx >> 8;
  float4 xc4 = *(const float4*)(xc + row * INNER_D + g * 4);
  float4 xm4 = *(const float4*)(xm + row * INNER_D + g * 4);
  const float* qg = qw + g * 16;
  const float* kg = kw + g * 16;
  const float* vg = vw + g * 16;
  float xcv[4] = {xc4.x, xc4.y, xc4.z, xc4.w};
  float xmv[4] = {xm4.x, xm4.y, xm4.z, xm4.w};
  ushort4 qs, ks, vs;
  u16* qp = (u16*)&qs; u16* kp = (u16*)&ks; u16* vp = (u16*)&vs;
#pragma unroll
  for (int o = 0; o < 4; o++) {
    float aq = 0.f, ak = 0.f, av = 0.f;
#pragma unroll
    for (int d = 0; d < 4; d++) {
      aq += xcv[d] * qg[o * 4 + d];
      ak += xcv[d] * kg[o * 4 + d];
      av += xmv[d] * vg[o * 4 + d];
    }
    qp[o] = f2bf(aq); kp[o] = f2bf(ak); vp[o] = f2bf(av);
  }
  size_t off = row * INNER_D + g * 4;
  *(ushort4*)(q + off) = qs;
  *(ushort4*)(k + off) = ks;
  *(ushort4*)(v + off) = vs;
}

// ---------------- gate GEMVs (bf16 inputs) ----------------
__global__ __launch_bounds__(256) void gates_kernel(
    const u16* __restrict__ q, const u16* __restrict__ k, const u16* __restrict__ v,
    const float* __restrict__ igW, const float* __restrict__ igb,
    const float* __restrict__ fgW, const float* __restrict__ fgb,
    float* __restrict__ ig, float* __restrict__ fg)
{
  int row = blockIdx.x;
  int b = row >> 10, s = row & (S_LEN - 1);
  int tid = threadIdx.x;
  float ia[8] = {}, fa[8] = {};
#pragma unroll
  for (int i = 0; i < 12; i++) {
    int j = tid + i * 256;
    float xv;
    if (j < 1024) xv = bf2f(q[(size_t)row * INNER_D + j]);
    else if (j < 2048) xv = bf2f(k[(size_t)row * INNER_D + j - 1024]);
    else xv = bf2f(v[(size_t)row * INNER_D + j - 2048]);
    float4 wi0 = *(const float4*)(igW + (size_t)j * 8);
    float4 wi1 = *(const float4*)(igW + (size_t)j * 8 + 4);
    float4 wf0 = *(const float4*)(fgW + (size_t)j * 8);
    float4 wf1 = *(const float4*)(fgW + (size_t)j * 8 + 4);
    ia[0] += xv * wi0.x; ia[1] += xv * wi0.y; ia[2] += xv * wi0.z; ia[3] += xv * wi0.w;
    ia[4] += xv * wi1.x; ia[5] += xv * wi1.y; ia[6] += xv * wi1.z; ia[7] += xv * wi1.w;
    fa[0] += xv * wf0.x; fa[1] += xv * wf0.y; fa[2] += xv * wf0.z; fa[3] += xv * wf0.w;
    fa[4] += xv * wf1.x; fa[5] += xv * wf1.y; fa[6] += xv * wf1.z; fa[7] += xv * wf1.w;
  }
#pragma unroll
  for (int off = 32; off; off >>= 1) {
#pragma unroll
    for (int n = 0; n < 8; n++) {
      ia[n] += __shfl_xor(ia[n], off);
      fa[n] += __shfl_xor(fa[n], off);
    }
  }
  __shared__ float red[2][4][8];
  int wv = tid >> 6;
  if ((tid & 63) == 0) {
#pragma unroll
    for (int n = 0; n < 8; n++) { red[0][wv][n] = ia[n]; red[1][wv][n] = fa[n]; }
  }
  __syncthreads();
  if (tid < 8) {
    float si = red[0][0][tid] + red[0][1][tid] + red[0][2][tid] + red[0][3][tid];
    float sf = red[1][0][tid] + red[1][1][tid] + red[1][2][tid] + red[1][3][tid];
    size_t o = ((size_t)(b * NHEAD + tid) << 10) + s;
    ig[o] = si + igb[tid];
    fg[o] = sf + fgb[tid];
  }
}

// ---------------- per-(b,h) scans, shuffle-based ----------------
__global__ __launch_bounds__(1024) void scan_kernel(
    const float* __restrict__ ig, const float* __restrict__ fg,
    float* __restrict__ a, float* __restrict__ rm, float* __restrict__ enm)
{
  int bh = blockIdx.x;
  int t = threadIdx.x;
  int lane = t & 63, wv = t >> 6;
  __shared__ float sw[16];
  size_t o = ((size_t)bh << 10) + t;
  float f = fg[o];
  float lf = (f >= 0.f) ? -log1pf(__expf(-f)) : f - log1pf(__expf(f));
  // wave-inclusive sum scan
  float v = lf;
#pragma unroll
  for (int off = 1; off < 64; off <<= 1) {
    float u = __shfl_up(v, off);
    if (lane >= off) v += u;
  }
  if (lane == 63) sw[wv] = v;
  __syncthreads();
  float pre = 0.f;
  for (int w = 0; w < wv; w++) pre += sw[w];
  float cs = v + pre;
  float av = ig[o] - cs;
  a[o] = av;
  // wave-inclusive max scan of av
  float m = av;
#pragma unroll
  for (int off = 1; off < 64; off <<= 1) {
    float u = __shfl_up(m, off);
    if (lane >= off) m = fmaxf(m, u);
  }
  __syncthreads();  // all sw reads done before reuse
  if (lane == 63) sw[wv] = m;
  __syncthreads();
  float pm = -3.4e38f;
  for (int w = 0; w < wv; w++) pm = fmaxf(pm, sw[w]);
  float rmx = fmaxf(m, pm);
  rm[o] = rmx;
  enm[o] = __expf(-(cs + rmx));
}

// ---------------- balanced split-K MFMA attention ----------------
// 24 jobs per bh, LPT-ordered (biggest first). mode 0 = full (inline epilogue),
// mode 1/2 = kt-range partial -> slot 0/1 of hpart/scpart (plain f32 stores).
__device__ __constant__ int c_qt[24] = {7,15,14,15, 6,13,14,12,13, 5,11,12,10,11, 4, 9,10, 8, 9, 3, 8, 2, 1, 0};
__device__ __constant__ int c_k0[24] = {0, 0, 7, 8, 0, 0, 0, 6, 7, 0, 0, 0, 5, 6, 0, 0, 0, 4, 5, 0, 0, 0, 0, 0};
__device__ __constant__ int c_k1[24] = {8, 8,15,16, 7, 7, 7,13,14, 6, 6, 6,11,12, 5, 5, 5, 9,10, 4, 4, 3, 2, 1};
__device__ __constant__ int c_md[24] = {0, 1, 2, 2, 0, 1, 1, 2, 2, 0, 1, 1, 2, 2, 0, 1, 1, 2, 2, 0, 1, 0, 0, 0};

__global__ __launch_bounds__(256) void attn_mfma_kernel(
    const u16* __restrict__ qhg, const u16* __restrict__ khg, const u16* __restrict__ vhg,
    const float* __restrict__ a_arr, const float* __restrict__ rm_arr, const float* __restrict__ enm_arr,
    const float* __restrict__ xc, const float* __restrict__ z,
    const float* __restrict__ skip, const float* __restrict__ onw,
    u16* __restrict__ hs, float* __restrict__ hpart, float* __restrict__ scpart)
{
  const int bh = blockIdx.x;     // 0..15 (linear id mod 8 = bh mod 8 -> XCD locality)
  const int job = blockIdx.y;    // 0..23
  const int qt = c_qt[job], k0t = c_k0[job], k1t = c_k1[job], mode = c_md[job];
  const int b = bh >> 3, h = bh & 7;
  const int s0 = qt * 64;
  const int tid = threadIdx.x;
  const int wave = tid >> 6, lane = tid & 63;
  const int lm = lane & 15, lq = lane >> 4;
  const size_t rowbase = (size_t)b * S_LEN;
  const int c0 = h * DHEAD;

  __shared__ u16 Ks[64 * 136];   // [t][d]
  __shared__ u16 Vt[128 * 72];   // [d][t]
  __shared__ u16 Ws[64 * 72];    // [s][t] wave-private bands
  __shared__ float as_[64];

  // Q fragments in registers (wave-private 16-row band)
  short8 aq[4];
  {
    const u16* qp = qhg + (rowbase + s0 + wave * 16 + lm) * INNER_D + c0 + lq * 8;
#pragma unroll
    for (int kc = 0; kc < 4; kc++) {
      S8 tmp; tmp.q = *(const uint4*)(qp + kc * 32);
      aq[kc] = tmp.v;
    }
  }
  float rmv[4];
#pragma unroll
  for (int r = 0; r < 4; r++)
    rmv[r] = rm_arr[(size_t)bh * S_LEN + s0 + wave * 16 + lq * 4 + r];

  f32x4 accH[8] = {};
  float sc_acc[4] = {0.f, 0.f, 0.f, 0.f};
  const float scale = 0.08838834764831845f;  // 1/sqrt(128)

  for (int kt = k0t; kt < k1t; kt++) {
    const int t0 = kt * 64;
    __syncthreads();
#pragma unroll
    for (int rep = 0; rep < 4; rep++) {
      int idx = rep * 256 + tid;
      int r = idx >> 4, seg = (idx & 15) * 8;
      *(uint4*)&Ks[r * 136 + seg] =
          *(const uint4*)(khg + (rowbase + t0 + r) * INNER_D + c0 + seg);
    }
#pragma unroll
    for (int rep = 0; rep < 4; rep++) {
      int idx = rep * 256 + tid;
      int t = idx & 63, dgrp = idx >> 6;
      S8 vv;
      vv.q = *(const uint4*)(vhg + (rowbase + t0 + t) * INNER_D + c0 + dgrp * 8);
#pragma unroll
      for (int j = 0; j < 8; j++) Vt[(dgrp * 8 + j) * 72 + t] = vv.u[j];
    }
    if (tid < 64) as_[tid] = a_arr[(size_t)bh * S_LEN + t0 + tid];
    __syncthreads();

    // phase A
    f32x4 pacc[4] = {};
#pragma unroll
    for (int kc = 0; kc < 4; kc++) {
#pragma unroll
      for (int cb = 0; cb < 4; cb++) {
        short8 bk = *(const short8*)&Ks[(cb * 16 + lm) * 136 + kc * 32 + lq * 8];
        pacc[cb] = __builtin_amdgcn_mfma_f32_16x16x32_bf16(aq[kc], bk, pacc[cb], 0, 0, 0);
      }
    }

    // w + causal mask; wave-private Ws; fp32 rowsum
    float wpart[4] = {0.f, 0.f, 0.f, 0.f};
#pragma unroll
    for (int cb = 0; cb < 4; cb++) {
      int colg = t0 + cb * 16 + lm;
      float ea = as_[cb * 16 + lm];
#pragma unroll
      for (int r = 0; r < 4; r++) {
        int rowg = s0 + wave * 16 + lq * 4 + r;
        float wv = pacc[cb][r] * scale * __expf(ea - rmv[r]);
        if (colg > rowg) wv = 0.f;
        wpart[r] += wv;
        Ws[(wave * 16 + lq * 4 + r) * 72 + cb * 16 + lm] = f2bf(wv);
      }
    }
#pragma unroll
    for (int r = 0; r < 4; r++) {
      float sr = wpart[r];
      sr += __shfl_xor(sr, 1); sr += __shfl_xor(sr, 2);
      sr += __shfl_xor(sr, 4); sr += __shfl_xor(sr, 8);
      sc_acc[r] += sr;
    }

    // phase B
#pragma unroll
    for (int kc = 0; kc < 2; kc++) {
      short8 aw = *(const short8*)&Ws[(wave * 16 + lm) * 72 + kc * 32 + lq * 8];
#pragma unroll
      for (int nb = 0; nb < 8; nb++) {
        short8 bv = *(const short8*)&Vt[(nb * 16 + lm) * 72 + kc * 32 + lq * 8];
        accH[nb] = __builtin_amdgcn_mfma_f32_16x16x32_bf16(aw, bv, accH[nb], 0, 0, 0);
      }
    }
  }

  if (mode != 0) {
    // write f32 partials (plain stores, no atomics)
    int slot = mode - 1;
    int qr = qt - 8;
    float* Hp = hpart + (((size_t)slot * 16 + bh) * 8 + qr) * 8192;
    float* sp = scpart + ((slot * 16 + bh) * 8 + qr) * 64;
#pragma unroll
    for (int r = 0; r < 4; r++) {
      int row = wave * 16 + lq * 4 + r;
      if (lm == 0) sp[row] = sc_acc[r];
#pragma unroll
      for (int nb = 0; nb < 8; nb++)
        Hp[row * 128 + nb * 16 + lm] = accH[nb][r];
    }
    return;
  }

  // mode 0: inline norm + headwise LN + epilogue
  float inv[4], muv[4], rsv[4];
#pragma unroll
  for (int r = 0; r < 4; r++) {
    int rowg = s0 + wave * 16 + lq * 4 + r;
    float nrm = fmaxf(fabsf(sc_acc[r]), enm_arr[(size_t)bh * S_LEN + rowg]);
    inv[r] = 1.f / (nrm + 1e-6f);
  }
#pragma unroll
  for (int r = 0; r < 4; r++) {
    float s = 0.f, qq = 0.f;
#pragma unroll
    for (int nb = 0; nb < 8; nb++) {
      float hv = accH[nb][r] * inv[r];
      accH[nb][r] = hv;
      s += hv; qq += hv * hv;
    }
    s += __shfl_xor(s, 1); s += __shfl_xor(s, 2); s += __shfl_xor(s, 4); s += __shfl_xor(s, 8);
    qq += __shfl_xor(qq, 1); qq += __shfl_xor(qq, 2); qq += __shfl_xor(qq, 4); qq += __shfl_xor(qq, 8);
    float mu = s * (1.f / DHEAD);
    float var = qq * (1.f / DHEAD) - mu * mu;
    muv[r] = mu;
    rsv[r] = rsqrtf(var + 1e-5f);
  }
  float ow[8], sk[8];
#pragma unroll
  for (int nb = 0; nb < 8; nb++) {
    ow[nb] = onw[c0 + nb * 16 + lm];
    sk[nb] = skip[c0 + nb * 16 + lm];
  }
#pragma unroll
  for (int r = 0; r < 4; r++) {
    int rowg = s0 + wave * 16 + lq * 4 + r;
    size_t base = (rowbase + rowg) * INNER_D + c0;
#pragma unroll
    for (int nb = 0; nb < 8; nb++) {
      int d = nb * 16 + lm;
      float xcv = xc[base + d];
      float zv = z[base + d];
      float hn = (accH[nb][r] - muv[r]) * rsv[r] * ow[nb] + sk[nb] * xcv;
      float o = hn * (zv / (1.f + __expf(-zv)));
      hs[base + d] = f2bf(o);
    }
  }
}

// combine two partial slots for rows s >= 512 (qt 8..15); one wave per row.
__global__ __launch_bounds__(256) void attn_combine_kernel(
    const float* __restrict__ hpart, const float* __restrict__ scpart,
    const float* __restrict__ enm,
    const float* __restrict__ xc, const float* __restrict__ z,
    const float* __restrict__ skip, const float* __restrict__ onw,
    u16* __restrict__ hs)
{
  int wave = threadIdx.x >> 6, lane = threadIdx.x & 63;
  int gid = blockIdx.x * 4 + wave;  // 0..8191
  int bh = gid >> 9;
  int rr = gid & 511;
  int qr = rr >> 6, row = rr & 63;
  int b = bh >> 3, hh = bh & 7;
  int s = (qr + 8) * 64 + row;
  size_t off = (((size_t)bh) * 8 + qr) * 8192 + row * 128 + lane * 2;
  float2 h0 = *(const float2*)(hpart + off);
  float2 h1 = *(const float2*)(hpart + 1048576 + off);
  int sidx = (bh * 8 + qr) * 64 + row;
  float sc = scpart[sidx] + scpart[8192 + sidx];
  float nrm = fmaxf(fabsf(sc), enm[(size_t)bh * S_LEN + s]);
  float inv = 1.f / (nrm + 1e-6f);
  float hx = (h0.x + h1.x) * inv, hy = (h0.y + h1.y) * inv;
  float sm = hx + hy, sq = hx * hx + hy * hy;
#pragma unroll
  for (int off2 = 32; off2; off2 >>= 1) { sm += __shfl_xor(sm, off2); sq += __shfl_xor(sq, off2); }
  float mu = sm * (1.f / DHEAD);
  float var = sq * (1.f / DHEAD) - mu * mu;
  float rs = rsqrtf(var + 1e-5f);
  int c0 = hh * DHEAD + lane * 2;
  size_t base = ((size_t)(b * S_LEN + s)) * INNER_D + c0;
  float2 xc2 = *(const float2*)(xc + base);
  float2 z2  = *(const float2*)(z + base);
  float skx = skip[c0], sky = skip[c0 + 1];
  float owx = onw[c0],  owy = onw[c0 + 1];
  ushort2 o;
  o.x = f2bf(((hx - mu) * rs * owx + skx * xc2.x) * (z2.x / (1.f + __expf(-z2.x))));
  o.y = f2bf(((hy - mu) * rs * owy + sky * xc2.y) * (z2.y / (1.f + __expf(-z2.y))));
  *(ushort2*)(hs + base) = o;
}

// ---------------- head ----------------
__global__ __launch_bounds__(64) void head_kernel(
    const float* __restrict__ ln96, const float* __restrict__ hW, const float* __restrict__ hb,
    float* __restrict__ out)
{
  int row = blockIdx.x;
  int n = threadIdx.x;
  if (n >= 21) return;
  float acc = hb[n];
  const float* xr = ln96 + (size_t)row * E_DIM;
  for (int kk = 0; kk < E_DIM; kk++) acc += xr[kk] * hW[kk * 21 + n];
  out[row * 21 + n] = acc;
}

extern "C" void kernel_launch(void* const* d_in, const int* in_sizes, int n_in,
                              void* d_out, int out_size, void* d_ws, size_t ws_size,
                              hipStream_t stream)
{
  const float* x_enc   = (const float*)d_in[0];
  const float* x_mark  = (const float*)d_in[1];
  const float* emb_W   = (const float*)d_in[4];
  const float* emb_b   = (const float*)d_in[5];
  const float* ln_w    = (const float*)d_in[6];
  const float* up_W    = (const float*)d_in[7];
  const float* conv_W  = (const float*)d_in[8];
  const float* conv_b  = (const float*)d_in[9];
  const float* q_W     = (const float*)d_in[10];
  const float* k_W     = (const float*)d_in[11];
  const float* v_W     = (const float*)d_in[12];
  const float* ig_W    = (const float*)d_in[13];
  const float* ig_b    = (const float*)d_in[14];
  const float* fg_W    = (const float*)d_in[15];
  const float* fg_b    = (const float*)d_in[16];
  const float* skip_w  = (const float*)d_in[17];
  const float* onorm_w = (const float*)d_in[18];
  const float* down_W  = (const float*)d_in[19];
  const float* post_ln = (const float*)d_in[20];
  const float* head_W  = (const float*)d_in[21];
  const float* head_b  = (const float*)d_in[22];

  float* p = (float*)d_ws;
  float* x    = p; p += 1048576;   // 2048*512 f32
  float* xm   = p; p += 2097152;   // 2048*1024 f32; reused as hsbh (bf16) after qkv
  float* z    = p; p += 2097152;
  float* xc   = p; p += 2097152;
  float* igb_ = p; p += 16384;
  float* fgb_ = p; p += 16384;
  float* ab   = p; p += 16384;
  float* rmb  = p; p += 16384;
  float* enmb = p; p += 16384;
  float* ln96 = p; p += 98304;
  u16* qhb = (u16*)p; p += 1048576;  // 2048*1024 u16
  u16* khb = (u16*)p; p += 1048576;
  u16* vhb = (u16*)p; p += 1048576;
  u16* xnh  = (u16*)p; p += 524288;  // 2048*512 u16
  u16* upWt = (u16*)p; p += 524288;
  u16* dnWt = (u16*)p; p += 262144;  // 512*1024 u16
  float* hpart = p; p += 2097152;    // 2 slots x 16 bh x 8 qt x 64 x 128 f32 (8 MB)
  float* scpart = p; p += 16384;     // 2 x 16 x 8 x 64
  u16* hsbh = (u16*)xm;
  // total ~14.1M floats = 56.4 MB (ws = 64 MiB)

  embed_kernel<<<2048, 128, 0, stream>>>(x_enc, x_mark, emb_W, emb_b, x);

  for (int L = 0; L < 4; L++) {
    ln_kernel<<<2048, 256, 0, stream>>>(x, ln_w + L * 512, xnh);
    transpose_bf16_kernel<<<dim3(8, 32), 256, 0, stream>>>(
        up_W + (size_t)L * 512 * 2048, upWt, 512, 2048);
    gemm_bf16<0><<<dim3(16, 16), 256, 0, stream>>>(
        xnh, upWt, xm, z, 2048, 2048, 512, 1024, 1024);
    conv_silu_kernel<<<2048, 256, 0, stream>>>(xm, conv_W + L * 4096, conv_b + L * 1024, xc);
    qkv_headwise_kernel<<<2048, 256, 0, stream>>>(
        xc, xm, q_W + L * 4096, k_W + L * 4096, v_W + L * 4096, qhb, khb, vhb);
    gates_kernel<<<2048, 256, 0, stream>>>(
        qhb, khb, vhb,
        ig_W + L * 24576, ig_b + L * 8, fg_W + L * 24576, fg_b + L * 8, igb_, fgb_);
    scan_kernel<<<16, 1024, 0, stream>>>(igb_, fgb_, ab, rmb, enmb);
    attn_mfma_kernel<<<dim3(16, 24), 256, 0, stream>>>(
        qhb, khb, vhb, ab, rmb, enmb, xc, z,
        skip_w + L * 1024, onorm_w + L * 1024, hsbh, hpart, scpart);
    attn_combine_kernel<<<2048, 256, 0, stream>>>(
        hpart, scpart, enmb, xc, z, skip_w + L * 1024, onorm_w + L * 1024, hsbh);
    transpose_bf16_kernel<<<dim3(16, 8), 256, 0, stream>>>(
        down_W + (size_t)L * 1024 * 512, dnWt, 1024, 512);
    gemm_bf16_64<1><<<dim3(8, 32), 256, 0, stream>>>(
        hsbh, dnWt, x, 2048, 512, 1024, 512);
  }

  ln_final_kernel<<<192, 256, 0, stream>>>(x, post_ln, ln96);
  head_kernel<<<192, 64, 0, stream>>>(ln96, head_W, head_b, (float*)d_out);
}